// Round 1
// baseline (549.140 us; speedup 1.0000x reference)
//
#include <hip/hip_runtime.h>

// Problem constants (B=1)
#define T_LEN 2048
#define C_DIM 1024
#define H_NUM 16
#define D_DIM 64
#define QKV_N (3 * H_NUM * D_DIM)   // 3072
#define L_CHK 64
#define NC (T_LEN / L_CHK)          // 32

// ---------------------------------------------------------------------------
// Generic NT SGEMM: C[M,N] = A[M,K] * B[N,K]^T, all row-major fp32.
// 64x64 block tile, BK=16, 256 threads, 4x4 per thread.
// ---------------------------------------------------------------------------
__global__ __launch_bounds__(256) void gemm_nt_64x64(
    const float* __restrict__ A, const float* __restrict__ B,
    float* __restrict__ C, int M, int N, int K) {
  __shared__ float As[16][65];
  __shared__ float Bs[16][65];
  const int tid = threadIdx.x;
  const int tx = tid % 16;        // N dir
  const int ty = tid / 16;        // M dir
  const int bm = blockIdx.y * 64;
  const int bn = blockIdx.x * 64;
  const int lr = tid / 4;         // 0..63 (tile row)
  const int lc = (tid % 4) * 4;   // 0,4,8,12 (k offset)
  const float* Ap = A + (size_t)(bm + lr) * K + lc;
  const float* Bp = B + (size_t)(bn + lr) * K + lc;
  float acc[4][4] = {};
  for (int k0 = 0; k0 < K; k0 += 16) {
    float4 a4 = *(const float4*)(Ap + k0);
    float4 b4 = *(const float4*)(Bp + k0);
    As[lc + 0][lr] = a4.x; As[lc + 1][lr] = a4.y;
    As[lc + 2][lr] = a4.z; As[lc + 3][lr] = a4.w;
    Bs[lc + 0][lr] = b4.x; Bs[lc + 1][lr] = b4.y;
    Bs[lc + 2][lr] = b4.z; Bs[lc + 3][lr] = b4.w;
    __syncthreads();
#pragma unroll
    for (int kk = 0; kk < 16; ++kk) {
      float a[4], b[4];
#pragma unroll
      for (int i = 0; i < 4; ++i) a[i] = As[kk][ty * 4 + i];
#pragma unroll
      for (int j = 0; j < 4; ++j) b[j] = Bs[kk][tx * 4 + j];
#pragma unroll
      for (int i = 0; i < 4; ++i)
#pragma unroll
        for (int j = 0; j < 4; ++j) acc[i][j] += a[i] * b[j];
    }
    __syncthreads();
  }
#pragma unroll
  for (int i = 0; i < 4; ++i)
#pragma unroll
    for (int j = 0; j < 4; ++j)
      C[(size_t)(bm + ty * 4 + i) * N + bn + tx * 4 + j] = acc[i][j];
}

// ---------------------------------------------------------------------------
// RoPE + split qkv (T,3072) -> q,k,v each [H][T][D]; rope on q,k only.
// ---------------------------------------------------------------------------
__global__ __launch_bounds__(256) void rope_split(
    const float* __restrict__ qkv, const float* __restrict__ cosb,
    const float* __restrict__ sinb, float* __restrict__ q,
    float* __restrict__ k, float* __restrict__ v) {
  int idx = blockIdx.x * 256 + threadIdx.x;  // == h*T*D + t*D + d
  int d = idx & 63;
  int t = (idx >> 6) & (T_LEN - 1);
  int h = idx >> 17;  // D*T = 2^17
  const float* base = qkv + (size_t)t * QKV_N + h * 3 * D_DIM;
  float c = cosb[t * D_DIM + d];
  float s = sinb[t * D_DIM + d];
  float qv = base[d];
  float kv = base[D_DIM + d];
  float vv = base[2 * D_DIM + d];
  float qr = (d < 32) ? -base[d + 32] : base[d - 32];
  float kr = (d < 32) ? -base[D_DIM + d + 32] : base[D_DIM + d - 32];
  q[idx] = qv * c + qr * s;
  k[idx] = kv * c + kr * s;
  v[idx] = vv;
}

// ---------------------------------------------------------------------------
// Per-(head,chunk) inclusive sums: kv[d][e] = sum_t k[t][d]*v[t][e],
// ksum[d], vsum[d].  One block per (h,c), 256 threads.
// ---------------------------------------------------------------------------
__global__ __launch_bounds__(256) void chunk_kv(
    const float* __restrict__ k, const float* __restrict__ v,
    float* __restrict__ kvchunk, float* __restrict__ kschunk,
    float* __restrict__ vschunk) {
  __shared__ float Ks[L_CHK][D_DIM];
  __shared__ float Vs[L_CHK][D_DIM];
  int blk = blockIdx.x;  // h*NC + c
  int h = blk / NC, c = blk % NC;
  const size_t off = ((size_t)h * T_LEN + c * L_CHK) * D_DIM;
  int tid = threadIdx.x;
#pragma unroll
  for (int m = 0; m < 4; ++m) {
    int el = (tid + m * 256) * 4;
    *(float4*)&((float*)Ks)[el] = *(const float4*)&k[off + el];
    *(float4*)&((float*)Vs)[el] = *(const float4*)&v[off + el];
  }
  __syncthreads();
  int e = tid & 63;
  int q2 = tid >> 6;  // 0..3
  float acc[16] = {};
  for (int t = 0; t < L_CHK; ++t) {
    float ve = Vs[t][e];
#pragma unroll
    for (int m = 0; m < 16; ++m) acc[m] += Ks[t][q2 * 16 + m] * ve;
  }
  float* outb = kvchunk + (size_t)blk * (D_DIM * D_DIM);
#pragma unroll
  for (int m = 0; m < 16; ++m) outb[(q2 * 16 + m) * D_DIM + e] = acc[m];
  if (tid < 64) {
    float s = 0.f;
    for (int t = 0; t < L_CHK; ++t) s += Ks[t][tid];
    kschunk[(size_t)blk * D_DIM + tid] = s;
  } else if (tid < 128) {
    float s = 0.f;
    for (int t = 0; t < L_CHK; ++t) s += Vs[t][tid - 64];
    vschunk[(size_t)blk * D_DIM + (tid - 64)] = s;
  }
}

// Exclusive prefix over chunks for the D*D state, per head.
__global__ __launch_bounds__(256) void scan_kv(
    const float* __restrict__ kvchunk, float* __restrict__ kvpref) {
  int gid = blockIdx.x * 256 + threadIdx.x;  // h*4096 + de (total 65536)
  int h = gid >> 12;
  int de = gid & 4095;
  float run = 0.f;
  for (int c = 0; c < NC; ++c) {
    size_t idx = ((size_t)(h * NC + c) << 12) + de;
    kvpref[idx] = run;
    run += kvchunk[idx];
  }
}

// Exclusive prefix over chunks for ksum/vsum vectors.
__global__ __launch_bounds__(256) void scan_vec(
    const float* __restrict__ kschunk, const float* __restrict__ vschunk,
    float* __restrict__ kspref, float* __restrict__ vspref) {
  int gid = blockIdx.x * 256 + threadIdx.x;  // h*64 + d (total 1024)
  int h = gid >> 6, d = gid & 63;
  float rk = 0.f, rv = 0.f;
  for (int c = 0; c < NC; ++c) {
    size_t idx = (size_t)(h * NC + c) * 64 + d;
    kspref[idx] = rk;
    vspref[idx] = rv;
    rk += kschunk[idx];
    rv += vschunk[idx];
  }
}

// ---------------------------------------------------------------------------
// Per-(head,chunk) output: y = (inter + intra numerator) / den, written in
// (T, H*D) layout for the projection GEMM.  64 threads = one row each.
// ---------------------------------------------------------------------------
__global__ __launch_bounds__(64) void attn_out(
    const float* __restrict__ q, const float* __restrict__ k,
    const float* __restrict__ v, const float* __restrict__ kvpref,
    const float* __restrict__ kspref, const float* __restrict__ vspref,
    float* __restrict__ y) {
  __shared__ float Qs[L_CHK][D_DIM];
  __shared__ float Ks[L_CHK][D_DIM];
  __shared__ float Vs[L_CHK][D_DIM];
  int blk = blockIdx.x;  // h*NC + c
  int h = blk / NC, c = blk % NC;
  int r = threadIdx.x;  // 0..63
  const size_t off = ((size_t)h * T_LEN + c * L_CHK) * D_DIM;
#pragma unroll
  for (int m = 0; m < 16; ++m) {
    int el = (r + m * 64) * 4;
    *(float4*)&((float*)Qs)[el] = *(const float4*)&q[off + el];
    *(float4*)&((float*)Ks)[el] = *(const float4*)&k[off + el];
    *(float4*)&((float*)Vs)[el] = *(const float4*)&v[off + el];
  }
  __syncthreads();
  float4 q4[16];
#pragma unroll
  for (int i = 0; i < 16; ++i) q4[i] = *(const float4*)&Qs[r][i * 4];

  const float* ksp = kspref + (size_t)blk * D_DIM;
  const float* vsp = vspref + (size_t)blk * D_DIM;
  const float* kvp = kvpref + (size_t)blk * (D_DIM * D_DIM);

  float den = (float)(c * L_CHK + r + 1);
#pragma unroll
  for (int i = 0; i < 16; ++i) {
    float4 kk = *(const float4*)&ksp[i * 4];
    den += q4[i].x * kk.x + q4[i].y * kk.y + q4[i].z * kk.z + q4[i].w * kk.w;
  }
  float4 num[16];
#pragma unroll
  for (int i = 0; i < 16; ++i) num[i] = *(const float4*)&vsp[i * 4];
  // inter: num += q @ KVpref   (KVpref rows broadcast across lanes)
  for (int d = 0; d < D_DIM; ++d) {
    float qd = Qs[r][d];
    const float4* row = (const float4*)&kvp[d * D_DIM];
#pragma unroll
    for (int j = 0; j < 16; ++j) {
      float4 kv4 = row[j];
      num[j].x += qd * kv4.x;
      num[j].y += qd * kv4.y;
      num[j].z += qd * kv4.z;
      num[j].w += qd * kv4.w;
    }
  }
  // intra: causal masked (1 + q.k_j) * v_j
  for (int j = 0; j < L_CHK; ++j) {
    float sdot = 0.f;
    const float4* krow = (const float4*)&Ks[j][0];
#pragma unroll
    for (int i = 0; i < 16; ++i) {
      float4 kj = krow[i];
      sdot += q4[i].x * kj.x + q4[i].y * kj.y + q4[i].z * kj.z + q4[i].w * kj.w;
    }
    float w = (j <= r) ? 1.f : 0.f;
    den += w * sdot;
    float f = w * (sdot + 1.f);
    const float4* vrow = (const float4*)&Vs[j][0];
#pragma unroll
    for (int i = 0; i < 16; ++i) {
      float4 vj = vrow[i];
      num[i].x += f * vj.x;
      num[i].y += f * vj.y;
      num[i].z += f * vj.z;
      num[i].w += f * vj.w;
    }
  }
  float inv = 1.f / den;
  int t = c * L_CHK + r;
  float* yrow = y + (size_t)t * (H_NUM * D_DIM) + h * D_DIM;
#pragma unroll
  for (int i = 0; i < 16; ++i) {
    float4 o;
    o.x = num[i].x * inv;
    o.y = num[i].y * inv;
    o.z = num[i].z * inv;
    o.w = num[i].w * inv;
    *(float4*)&yrow[i * 4] = o;
  }
}

// ---------------------------------------------------------------------------
extern "C" void kernel_launch(void* const* d_in, const int* in_sizes, int n_in,
                              void* d_out, int out_size, void* d_ws,
                              size_t ws_size, hipStream_t stream) {
  const float* x = (const float*)d_in[0];       // (1,2048,1024)
  const float* w_attn = (const float*)d_in[1];  // (3072,1024)
  const float* w_proj = (const float*)d_in[2];  // (1024,1024)
  const float* cosb = (const float*)d_in[3];    // (2048,64)
  const float* sinb = (const float*)d_in[4];    // (2048,64)
  float* out = (float*)d_out;                   // (2048,1024)

  float* ws = (float*)d_ws;
  float* qkv = ws;                          // 2048*3072
  float* qbuf = qkv + (size_t)T_LEN * QKV_N;
  float* kbuf = qbuf + (size_t)H_NUM * T_LEN * D_DIM;
  float* vbuf = kbuf + (size_t)H_NUM * T_LEN * D_DIM;
  float* kvchunk = vbuf + (size_t)H_NUM * T_LEN * D_DIM;  // 16*32*4096
  float* kvpref = kvchunk + (size_t)H_NUM * NC * D_DIM * D_DIM;
  float* kschunk = kvpref + (size_t)H_NUM * NC * D_DIM * D_DIM;
  float* vschunk = kschunk + (size_t)H_NUM * NC * D_DIM;
  float* kspref = vschunk + (size_t)H_NUM * NC * D_DIM;
  float* vspref = kspref + (size_t)H_NUM * NC * D_DIM;
  float* ybuf = vspref + (size_t)H_NUM * NC * D_DIM;  // 2048*1024

  // 1) qkv = x @ w_attn^T : M=2048, N=3072, K=1024
  {
    dim3 grid(QKV_N / 64, T_LEN / 64);
    gemm_nt_64x64<<<grid, 256, 0, stream>>>(x, w_attn, qkv, T_LEN, QKV_N,
                                            C_DIM);
  }
  // 2) rope + split
  rope_split<<<(H_NUM * T_LEN * D_DIM) / 256, 256, 0, stream>>>(
      qkv, cosb, sinb, qbuf, kbuf, vbuf);
  // 3) per-chunk sums
  chunk_kv<<<H_NUM * NC, 256, 0, stream>>>(kbuf, vbuf, kvchunk, kschunk,
                                           vschunk);
  // 4) prefix scans
  scan_kv<<<(H_NUM * D_DIM * D_DIM) / 256, 256, 0, stream>>>(kvchunk, kvpref);
  scan_vec<<<(H_NUM * D_DIM) / 256, 256, 0, stream>>>(kschunk, vschunk, kspref,
                                                      vspref);
  // 5) attention output -> y in (T, H*D) layout
  attn_out<<<H_NUM * NC, 64, 0, stream>>>(qbuf, kbuf, vbuf, kvpref, kspref,
                                          vspref, ybuf);
  // 6) out = y @ w_proj^T : M=2048, N=1024, K=1024
  {
    dim3 grid(C_DIM / 64, T_LEN / 64);
    gemm_nt_64x64<<<grid, 256, 0, stream>>>(ybuf, w_proj, out, T_LEN, C_DIM,
                                            C_DIM);
  }
}

// Round 3
// 314.166 us; speedup vs baseline: 1.7479x; 1.7479x over previous
//
#include <hip/hip_runtime.h>

// Problem constants (B=1)
#define T_LEN 2048
#define C_DIM 1024
#define H_NUM 16
#define D_DIM 64
#define QKV_N (3 * H_NUM * D_DIM)   // 3072
#define L_CHK 64
#define NC (T_LEN / L_CHK)          // 32
#define LDS_STRIDE 40               // halves; 80B rows, 16B-aligned frags

typedef _Float16 h8 __attribute__((ext_vector_type(8)));
typedef float f32x4 __attribute__((ext_vector_type(4)));

// ---------------------------------------------------------------------------
// fp32 -> (hi,lo) fp16 split with pre-scale. v = in*scale; hi = f16(v);
// lo = f16(v - hi). 8 elems/thread.
// ---------------------------------------------------------------------------
__global__ __launch_bounds__(256) void split_f16(
    const float* __restrict__ in, _Float16* __restrict__ hi,
    _Float16* __restrict__ lo, int n, float scale) {
  int i = (blockIdx.x * 256 + threadIdx.x) * 8;
  if (i >= n) return;
  float4 a = *(const float4*)(in + i);
  float4 b = *(const float4*)(in + i + 4);
  float v[8] = {a.x, a.y, a.z, a.w, b.x, b.y, b.z, b.w};
  h8 hv, lv;
#pragma unroll
  for (int j = 0; j < 8; ++j) {
    float s = v[j] * scale;
    _Float16 h = (_Float16)s;
    hv[j] = h;
    lv[j] = (_Float16)(s - (float)h);
  }
  *(h8*)(hi + i) = hv;
  *(h8*)(lo + i) = lv;
}

// ---------------------------------------------------------------------------
// Split-precision fp16 NT MFMA GEMM: C = outscale * (A*B^T) with
// A ~ Ah+Al, B ~ Bh+Bl. 128x128 tile, BK=32, 256 thr = 2x2 waves of 64x64.
// acc += Ah*Bh + Ah*Bl + Al*Bh (3 MFMAs, one fp32 accumulator).
// Explicit reg->LDS staging; LDS row stride 40 halves.
// ---------------------------------------------------------------------------
__global__ __launch_bounds__(256) void gemm_nt_f16x3(
    const _Float16* __restrict__ Ah, const _Float16* __restrict__ Al,
    const _Float16* __restrict__ Bh, const _Float16* __restrict__ Bl,
    float* __restrict__ C, int M, int N, int K, float outscale) {
  __shared__ _Float16 sAh[128 * LDS_STRIDE];
  __shared__ _Float16 sAl[128 * LDS_STRIDE];
  __shared__ _Float16 sBh[128 * LDS_STRIDE];
  __shared__ _Float16 sBl[128 * LDS_STRIDE];
  const int tid = threadIdx.x;
  const int wave = tid >> 6;
  const int lane = tid & 63;
  const int bm = blockIdx.y * 128;
  const int bn = blockIdx.x * 128;
  const int wm = wave >> 1;
  const int wn = wave & 1;
  const int quad = lane >> 4;
  const int lrow = lane & 15;

  f32x4 acc[4][4];
#pragma unroll
  for (int i = 0; i < 4; ++i)
#pragma unroll
    for (int j = 0; j < 4; ++j) acc[i][j] = (f32x4){0.f, 0.f, 0.f, 0.f};

  for (int k0 = 0; k0 < K; k0 += 32) {
#pragma unroll
    for (int it = 0; it < 2; ++it) {
      const int p = tid + it * 256;        // 0..511
      const int row = p >> 2;              // 0..127
      const int col = (p & 3) * 8;         // 0,8,16,24
      const size_t ga = (size_t)(bm + row) * K + k0 + col;
      const size_t gb = (size_t)(bn + row) * K + k0 + col;
      const int ld = row * LDS_STRIDE + col;
      *(h8*)&sAh[ld] = *(const h8*)&Ah[ga];
      *(h8*)&sAl[ld] = *(const h8*)&Al[ga];
      *(h8*)&sBh[ld] = *(const h8*)&Bh[gb];
      *(h8*)&sBl[ld] = *(const h8*)&Bl[gb];
    }
    __syncthreads();
    h8 ah[4], al[4], bh[4], bl[4];
#pragma unroll
    for (int i = 0; i < 4; ++i) {
      const int ra = (wm * 64 + i * 16 + lrow) * LDS_STRIDE + quad * 8;
      const int rb = (wn * 64 + i * 16 + lrow) * LDS_STRIDE + quad * 8;
      ah[i] = *(const h8*)&sAh[ra];
      al[i] = *(const h8*)&sAl[ra];
      bh[i] = *(const h8*)&sBh[rb];
      bl[i] = *(const h8*)&sBl[rb];
    }
#pragma unroll
    for (int i = 0; i < 4; ++i)
#pragma unroll
      for (int j = 0; j < 4; ++j) {
        acc[i][j] = __builtin_amdgcn_mfma_f32_16x16x32_f16(ah[i], bh[j],
                                                           acc[i][j], 0, 0, 0);
        acc[i][j] = __builtin_amdgcn_mfma_f32_16x16x32_f16(ah[i], bl[j],
                                                           acc[i][j], 0, 0, 0);
        acc[i][j] = __builtin_amdgcn_mfma_f32_16x16x32_f16(al[i], bh[j],
                                                           acc[i][j], 0, 0, 0);
      }
    __syncthreads();
  }
  // epilogue: C/D layout col=lane&15, row=quad*4+reg (m89/m91 verified)
#pragma unroll
  for (int i = 0; i < 4; ++i) {
    const int rbase = bm + wm * 64 + i * 16 + quad * 4;
#pragma unroll
    for (int j = 0; j < 4; ++j) {
      const int col = bn + wn * 64 + j * 16 + lrow;
#pragma unroll
      for (int r = 0; r < 4; ++r)
        C[(size_t)(rbase + r) * N + col] = acc[i][j][r] * outscale;
    }
  }
}

// ---------------------------------------------------------------------------
// RoPE + split qkv (T,3072) -> q,k,v each [H][T][D]; rope on q,k only.
// ---------------------------------------------------------------------------
__global__ __launch_bounds__(256) void rope_split(
    const float* __restrict__ qkv, const float* __restrict__ cosb,
    const float* __restrict__ sinb, float* __restrict__ q,
    float* __restrict__ k, float* __restrict__ v) {
  int idx = blockIdx.x * 256 + threadIdx.x;  // == h*T*D + t*D + d
  int d = idx & 63;
  int t = (idx >> 6) & (T_LEN - 1);
  int h = idx >> 17;  // D*T = 2^17
  const float* base = qkv + (size_t)t * QKV_N + h * 3 * D_DIM;
  float c = cosb[t * D_DIM + d];
  float s = sinb[t * D_DIM + d];
  float qv = base[d];
  float kv = base[D_DIM + d];
  float vv = base[2 * D_DIM + d];
  float qr = (d < 32) ? -base[d + 32] : base[d - 32];
  float kr = (d < 32) ? -base[D_DIM + d + 32] : base[D_DIM + d - 32];
  q[idx] = qv * c + qr * s;
  k[idx] = kv * c + kr * s;
  v[idx] = vv;
}

// ---------------------------------------------------------------------------
// Per-(head,chunk) sums: kv[d][e], ksum[d], vsum[d]. One block per (h,c).
// ---------------------------------------------------------------------------
__global__ __launch_bounds__(256) void chunk_kv(
    const float* __restrict__ k, const float* __restrict__ v,
    float* __restrict__ kvchunk, float* __restrict__ kschunk,
    float* __restrict__ vschunk) {
  __shared__ float Ks[L_CHK][D_DIM];
  __shared__ float Vs[L_CHK][D_DIM];
  int blk = blockIdx.x;  // h*NC + c
  const size_t off = ((size_t)(blk / NC) * T_LEN + (blk % NC) * L_CHK) * D_DIM;
  int tid = threadIdx.x;
#pragma unroll
  for (int m = 0; m < 4; ++m) {
    int el = (tid + m * 256) * 4;
    *(float4*)&((float*)Ks)[el] = *(const float4*)&k[off + el];
    *(float4*)&((float*)Vs)[el] = *(const float4*)&v[off + el];
  }
  __syncthreads();
  int e = tid & 63;
  int q2 = tid >> 6;  // 0..3
  float acc[16] = {};
  for (int t = 0; t < L_CHK; ++t) {
    float ve = Vs[t][e];
#pragma unroll
    for (int m = 0; m < 16; ++m) acc[m] += Ks[t][q2 * 16 + m] * ve;
  }
  float* outb = kvchunk + (size_t)blk * (D_DIM * D_DIM);
#pragma unroll
  for (int m = 0; m < 16; ++m) outb[(q2 * 16 + m) * D_DIM + e] = acc[m];
  if (tid < 64) {
    float s = 0.f;
    for (int t = 0; t < L_CHK; ++t) s += Ks[t][tid];
    kschunk[(size_t)blk * D_DIM + tid] = s;
  } else if (tid < 128) {
    float s = 0.f;
    for (int t = 0; t < L_CHK; ++t) s += Vs[t][tid - 64];
    vschunk[(size_t)blk * D_DIM + (tid - 64)] = s;
  }
}

// Exclusive prefix over chunks for the D*D state, per head.
__global__ __launch_bounds__(256) void scan_kv(
    const float* __restrict__ kvchunk, float* __restrict__ kvpref) {
  int gid = blockIdx.x * 256 + threadIdx.x;  // h*4096 + de
  int h = gid >> 12;
  int de = gid & 4095;
  float run = 0.f;
  for (int c = 0; c < NC; ++c) {
    size_t idx = ((size_t)(h * NC + c) << 12) + de;
    kvpref[idx] = run;
    run += kvchunk[idx];
  }
}

// Exclusive prefix over chunks for ksum/vsum vectors.
__global__ __launch_bounds__(256) void scan_vec(
    const float* __restrict__ kschunk, const float* __restrict__ vschunk,
    float* __restrict__ kspref, float* __restrict__ vspref) {
  int gid = blockIdx.x * 256 + threadIdx.x;  // h*64 + d (total 1024)
  int h = gid >> 6, d = gid & 63;
  float rk = 0.f, rv = 0.f;
  for (int c = 0; c < NC; ++c) {
    size_t idx = (size_t)(h * NC + c) * 64 + d;
    kspref[idx] = rk;
    vspref[idx] = rv;
    rk += kschunk[idx];
    rv += vschunk[idx];
  }
}

// ---------------------------------------------------------------------------
// Per-(head,chunk) output -> ybuf (T, H*D) fp32.
// ---------------------------------------------------------------------------
__global__ __launch_bounds__(64) void attn_out(
    const float* __restrict__ q, const float* __restrict__ k,
    const float* __restrict__ v, const float* __restrict__ kvpref,
    const float* __restrict__ kspref, const float* __restrict__ vspref,
    float* __restrict__ y) {
  __shared__ float Qs[L_CHK][D_DIM];
  __shared__ float Ks[L_CHK][D_DIM];
  __shared__ float Vs[L_CHK][D_DIM];
  int blk = blockIdx.x;  // h*NC + c
  int h = blk / NC, c = blk % NC;
  int r = threadIdx.x;  // 0..63
  const size_t off = ((size_t)h * T_LEN + c * L_CHK) * D_DIM;
#pragma unroll
  for (int m = 0; m < 16; ++m) {
    int el = (r + m * 64) * 4;
    *(float4*)&((float*)Qs)[el] = *(const float4*)&q[off + el];
    *(float4*)&((float*)Ks)[el] = *(const float4*)&k[off + el];
    *(float4*)&((float*)Vs)[el] = *(const float4*)&v[off + el];
  }
  __syncthreads();
  float4 q4[16];
#pragma unroll
  for (int i = 0; i < 16; ++i) q4[i] = *(const float4*)&Qs[r][i * 4];

  const float* ksp = kspref + (size_t)blk * D_DIM;
  const float* vsp = vspref + (size_t)blk * D_DIM;
  const float* kvp = kvpref + (size_t)blk * (D_DIM * D_DIM);

  float den = (float)(c * L_CHK + r + 1);
#pragma unroll
  for (int i = 0; i < 16; ++i) {
    float4 kk = *(const float4*)&ksp[i * 4];
    den += q4[i].x * kk.x + q4[i].y * kk.y + q4[i].z * kk.z + q4[i].w * kk.w;
  }
  float4 num[16];
#pragma unroll
  for (int i = 0; i < 16; ++i) num[i] = *(const float4*)&vsp[i * 4];
  for (int d = 0; d < D_DIM; ++d) {
    float qd = Qs[r][d];
    const float4* row = (const float4*)&kvp[d * D_DIM];
#pragma unroll
    for (int j = 0; j < 16; ++j) {
      float4 kv4 = row[j];
      num[j].x += qd * kv4.x;
      num[j].y += qd * kv4.y;
      num[j].z += qd * kv4.z;
      num[j].w += qd * kv4.w;
    }
  }
  for (int j = 0; j < L_CHK; ++j) {
    float sdot = 0.f;
    const float4* krow = (const float4*)&Ks[j][0];
#pragma unroll
    for (int i = 0; i < 16; ++i) {
      float4 kj = krow[i];
      sdot += q4[i].x * kj.x + q4[i].y * kj.y + q4[i].z * kj.z + q4[i].w * kj.w;
    }
    float w = (j <= r) ? 1.f : 0.f;
    den += w * sdot;
    float f = w * (sdot + 1.f);
    const float4* vrow = (const float4*)&Vs[j][0];
#pragma unroll
    for (int i = 0; i < 16; ++i) {
      float4 vj = vrow[i];
      num[i].x += f * vj.x;
      num[i].y += f * vj.y;
      num[i].z += f * vj.z;
      num[i].w += f * vj.w;
    }
  }
  float inv = 1.f / den;
  int t = c * L_CHK + r;
  float* yrow = y + (size_t)t * (H_NUM * D_DIM) + h * D_DIM;
#pragma unroll
  for (int i = 0; i < 16; ++i) {
    float4 o;
    o.x = num[i].x * inv;
    o.y = num[i].y * inv;
    o.z = num[i].z * inv;
    o.w = num[i].w * inv;
    *(float4*)&yrow[i * 4] = o;
  }
}

// ---------------------------------------------------------------------------
extern "C" void kernel_launch(void* const* d_in, const int* in_sizes, int n_in,
                              void* d_out, int out_size, void* d_ws,
                              size_t ws_size, hipStream_t stream) {
  const float* x = (const float*)d_in[0];       // (1,2048,1024)
  const float* w_attn = (const float*)d_in[1];  // (3072,1024)
  const float* w_proj = (const float*)d_in[2];  // (1024,1024)
  const float* cosb = (const float*)d_in[3];    // (2048,64)
  const float* sinb = (const float*)d_in[4];    // (2048,64)
  float* out = (float*)d_out;                   // (2048,1024)

  char* ws = (char*)d_ws;
  // Region A (0..24MB): qkv fp32 (live GEMM->rope); then kvchunk/kvpref/ybuf.
  float* qkv = (float*)ws;
  float* kvchunk = (float*)ws;                       // 8 MB  (after rope)
  float* kvpref = (float*)(ws + 8388608);            // 8 MB
  float* ybuf = (float*)(ws + 16777216);             // 8 MB fp32
  // Region B (24..48MB): q/k/v fp32
  float* qbuf = (float*)(ws + 25165824);
  float* kbuf = (float*)(ws + 25165824 + 8388608);
  float* vbuf = (float*)(ws + 25165824 + 16777216);
  // Region C (48..56MB): xh/xl (live split->QKV GEMM); then yh/yl.
  _Float16* xh = (_Float16*)(ws + 50331648);
  _Float16* xl = (_Float16*)(ws + 50331648 + 4194304);
  _Float16* yh = (_Float16*)(ws + 50331648);
  _Float16* yl = (_Float16*)(ws + 50331648 + 4194304);
  // Region D (56..68MB): wah/wal (live split->QKV GEMM); then scan vectors.
  _Float16* wah = (_Float16*)(ws + 58720256);
  _Float16* wal = (_Float16*)(ws + 58720256 + 6291456);
  float* kschunk = (float*)(ws + 58720256);
  float* vschunk = (float*)(ws + 58720256 + 131072);
  float* kspref = (float*)(ws + 58720256 + 262144);
  float* vspref = (float*)(ws + 58720256 + 393216);
  // Region E (68..72MB): wph/wpl (live whole call).
  _Float16* wph = (_Float16*)(ws + 71303168);
  _Float16* wpl = (_Float16*)(ws + 71303168 + 2097152);

  // 0) splits: x*64, w_attn*64, w_proj*64 (pow2 scales; undone in epilogues)
  split_f16<<<(T_LEN * C_DIM / 8 + 255) / 256, 256, 0, stream>>>(
      x, xh, xl, T_LEN * C_DIM, 64.f);
  split_f16<<<(QKV_N * C_DIM / 8 + 255) / 256, 256, 0, stream>>>(
      w_attn, wah, wal, QKV_N * C_DIM, 64.f);
  split_f16<<<(C_DIM * C_DIM / 8 + 255) / 256, 256, 0, stream>>>(
      w_proj, wph, wpl, C_DIM * C_DIM, 64.f);

  // 1) qkv = x @ w_attn^T : M=2048, N=3072, K=1024; scale 2^-12
  {
    dim3 grid(QKV_N / 128, T_LEN / 128);
    gemm_nt_f16x3<<<grid, 256, 0, stream>>>(xh, xl, wah, wal, qkv, T_LEN,
                                            QKV_N, C_DIM, 1.f / 4096.f);
  }
  // 2) rope + split
  rope_split<<<(H_NUM * T_LEN * D_DIM) / 256, 256, 0, stream>>>(
      qkv, cosb, sinb, qbuf, kbuf, vbuf);
  // 3) per-chunk sums (region A/D reused from here)
  chunk_kv<<<H_NUM * NC, 256, 0, stream>>>(kbuf, vbuf, kvchunk, kschunk,
                                           vschunk);
  // 4) prefix scans
  scan_kv<<<(H_NUM * D_DIM * D_DIM) / 256, 256, 0, stream>>>(kvchunk, kvpref);
  scan_vec<<<(H_NUM * D_DIM) / 256, 256, 0, stream>>>(kschunk, vschunk, kspref,
                                                      vspref);
  // 5) attention output -> ybuf (T, H*D) fp32
  attn_out<<<H_NUM * NC, 64, 0, stream>>>(qbuf, kbuf, vbuf, kvpref, kspref,
                                          vspref, ybuf);
  // 6) split y (scale 1; |y| < 65504 checked: max ~2.4e3)
  split_f16<<<(T_LEN * C_DIM / 8 + 255) / 256, 256, 0, stream>>>(
      ybuf, yh, yl, T_LEN * C_DIM, 1.f);
  // 7) out = y @ w_proj^T : M=2048, N=1024, K=1024; scale 2^-6
  {
    dim3 grid(C_DIM / 128, T_LEN / 128);
    gemm_nt_f16x3<<<grid, 256, 0, stream>>>(yh, yl, wph, wpl, out, T_LEN,
                                            C_DIM, C_DIM, 1.f / 64.f);
  }
}

// Round 4
// 227.244 us; speedup vs baseline: 2.4165x; 1.3825x over previous
//
#include <hip/hip_runtime.h>

// Problem constants (B=1)
#define T_LEN 2048
#define C_DIM 1024
#define H_NUM 16
#define D_DIM 64
#define QKV_N (3 * H_NUM * D_DIM)   // 3072
#define L_CHK 64
#define NC (T_LEN / L_CHK)          // 32
#define LDS_STRIDE 40               // halves; 80B rows, 16B-aligned frags

typedef _Float16 h8 __attribute__((ext_vector_type(8)));
typedef _Float16 h4 __attribute__((ext_vector_type(4)));
typedef float f32x4 __attribute__((ext_vector_type(4)));

// ---------------------------------------------------------------------------
// fp32 -> (hi,lo) fp16 split with pre-scale. v = in*scale; hi = f16(v);
// lo = f16(v - hi). 8 elems/thread.
// ---------------------------------------------------------------------------
__global__ __launch_bounds__(256) void split_f16(
    const float* __restrict__ in, _Float16* __restrict__ hi,
    _Float16* __restrict__ lo, int n, float scale) {
  int i = (blockIdx.x * 256 + threadIdx.x) * 8;
  if (i >= n) return;
  float4 a = *(const float4*)(in + i);
  float4 b = *(const float4*)(in + i + 4);
  float v[8] = {a.x, a.y, a.z, a.w, b.x, b.y, b.z, b.w};
  h8 hv, lv;
#pragma unroll
  for (int j = 0; j < 8; ++j) {
    float s = v[j] * scale;
    _Float16 h = (_Float16)s;
    hv[j] = h;
    lv[j] = (_Float16)(s - (float)h);
  }
  *(h8*)(hi + i) = hv;
  *(h8*)(lo + i) = lv;
}

// ---------------------------------------------------------------------------
// Split-precision fp16 NT MFMA GEMM: C = outscale * (A*B^T) with
// A ~ Ah+Al, B ~ Bh+Bl. 128x128 tile, BK=32, 256 thr = 2x2 waves of 64x64.
// acc += Ah*Bh + Ah*Bl + Al*Bh (3 MFMAs, one fp32 accumulator).
// ---------------------------------------------------------------------------
__global__ __launch_bounds__(256) void gemm_nt_f16x3(
    const _Float16* __restrict__ Ah, const _Float16* __restrict__ Al,
    const _Float16* __restrict__ Bh, const _Float16* __restrict__ Bl,
    float* __restrict__ C, int M, int N, int K, float outscale) {
  __shared__ _Float16 sAh[128 * LDS_STRIDE];
  __shared__ _Float16 sAl[128 * LDS_STRIDE];
  __shared__ _Float16 sBh[128 * LDS_STRIDE];
  __shared__ _Float16 sBl[128 * LDS_STRIDE];
  const int tid = threadIdx.x;
  const int wave = tid >> 6;
  const int lane = tid & 63;
  const int bm = blockIdx.y * 128;
  const int bn = blockIdx.x * 128;
  const int wm = wave >> 1;
  const int wn = wave & 1;
  const int quad = lane >> 4;
  const int lrow = lane & 15;

  f32x4 acc[4][4];
#pragma unroll
  for (int i = 0; i < 4; ++i)
#pragma unroll
    for (int j = 0; j < 4; ++j) acc[i][j] = (f32x4){0.f, 0.f, 0.f, 0.f};

  for (int k0 = 0; k0 < K; k0 += 32) {
#pragma unroll
    for (int it = 0; it < 2; ++it) {
      const int p = tid + it * 256;        // 0..511
      const int row = p >> 2;              // 0..127
      const int col = (p & 3) * 8;         // 0,8,16,24
      const size_t ga = (size_t)(bm + row) * K + k0 + col;
      const size_t gb = (size_t)(bn + row) * K + k0 + col;
      const int ld = row * LDS_STRIDE + col;
      *(h8*)&sAh[ld] = *(const h8*)&Ah[ga];
      *(h8*)&sAl[ld] = *(const h8*)&Al[ga];
      *(h8*)&sBh[ld] = *(const h8*)&Bh[gb];
      *(h8*)&sBl[ld] = *(const h8*)&Bl[gb];
    }
    __syncthreads();
    h8 ah[4], al[4], bh[4], bl[4];
#pragma unroll
    for (int i = 0; i < 4; ++i) {
      const int ra = (wm * 64 + i * 16 + lrow) * LDS_STRIDE + quad * 8;
      const int rb = (wn * 64 + i * 16 + lrow) * LDS_STRIDE + quad * 8;
      ah[i] = *(const h8*)&sAh[ra];
      al[i] = *(const h8*)&sAl[ra];
      bh[i] = *(const h8*)&sBh[rb];
      bl[i] = *(const h8*)&sBl[rb];
    }
#pragma unroll
    for (int i = 0; i < 4; ++i)
#pragma unroll
      for (int j = 0; j < 4; ++j) {
        acc[i][j] = __builtin_amdgcn_mfma_f32_16x16x32_f16(ah[i], bh[j],
                                                           acc[i][j], 0, 0, 0);
        acc[i][j] = __builtin_amdgcn_mfma_f32_16x16x32_f16(ah[i], bl[j],
                                                           acc[i][j], 0, 0, 0);
        acc[i][j] = __builtin_amdgcn_mfma_f32_16x16x32_f16(al[i], bh[j],
                                                           acc[i][j], 0, 0, 0);
      }
    __syncthreads();
  }
  // epilogue: C/D layout col=lane&15, row=quad*4+reg
#pragma unroll
  for (int i = 0; i < 4; ++i) {
    const int rbase = bm + wm * 64 + i * 16 + quad * 4;
#pragma unroll
    for (int j = 0; j < 4; ++j) {
      const int col = bn + wn * 64 + j * 16 + lrow;
#pragma unroll
      for (int r = 0; r < 4; ++r)
        C[(size_t)(rbase + r) * N + col] = acc[i][j][r] * outscale;
    }
  }
}

// ---------------------------------------------------------------------------
// RoPE + split qkv (T,3072) -> q,k,v each [H][T][D]; rope on q,k only.
// ---------------------------------------------------------------------------
__global__ __launch_bounds__(256) void rope_split(
    const float* __restrict__ qkv, const float* __restrict__ cosb,
    const float* __restrict__ sinb, float* __restrict__ q,
    float* __restrict__ k, float* __restrict__ v) {
  int idx = blockIdx.x * 256 + threadIdx.x;  // == h*T*D + t*D + d
  int d = idx & 63;
  int t = (idx >> 6) & (T_LEN - 1);
  int h = idx >> 17;  // D*T = 2^17
  const float* base = qkv + (size_t)t * QKV_N + h * 3 * D_DIM;
  float c = cosb[t * D_DIM + d];
  float s = sinb[t * D_DIM + d];
  float qv = base[d];
  float kv = base[D_DIM + d];
  float vv = base[2 * D_DIM + d];
  float qr = (d < 32) ? -base[d + 32] : base[d - 32];
  float kr = (d < 32) ? -base[D_DIM + d + 32] : base[D_DIM + d - 32];
  q[idx] = qv * c + qr * s;
  k[idx] = kv * c + kr * s;
  v[idx] = vv;
}

// ---------------------------------------------------------------------------
// Per-(head,chunk) sums: kv[d][e], ksum[d], vsum[d]. One block per (h,c).
// ---------------------------------------------------------------------------
__global__ __launch_bounds__(256) void chunk_kv(
    const float* __restrict__ k, const float* __restrict__ v,
    float* __restrict__ kvchunk, float* __restrict__ kschunk,
    float* __restrict__ vschunk) {
  __shared__ float Ks[L_CHK][D_DIM];
  __shared__ float Vs[L_CHK][D_DIM];
  int blk = blockIdx.x;  // h*NC + c
  const size_t off = ((size_t)(blk / NC) * T_LEN + (blk % NC) * L_CHK) * D_DIM;
  int tid = threadIdx.x;
#pragma unroll
  for (int m = 0; m < 4; ++m) {
    int el = (tid + m * 256) * 4;
    *(float4*)&((float*)Ks)[el] = *(const float4*)&k[off + el];
    *(float4*)&((float*)Vs)[el] = *(const float4*)&v[off + el];
  }
  __syncthreads();
  int e = tid & 63;
  int q2 = tid >> 6;  // 0..3
  float acc[16] = {};
  for (int t = 0; t < L_CHK; ++t) {
    float ve = Vs[t][e];
#pragma unroll
    for (int m = 0; m < 16; ++m) acc[m] += Ks[t][q2 * 16 + m] * ve;
  }
  float* outb = kvchunk + (size_t)blk * (D_DIM * D_DIM);
#pragma unroll
  for (int m = 0; m < 16; ++m) outb[(q2 * 16 + m) * D_DIM + e] = acc[m];
  if (tid < 64) {
    float s = 0.f;
    for (int t = 0; t < L_CHK; ++t) s += Ks[t][tid];
    kschunk[(size_t)blk * D_DIM + tid] = s;
  } else if (tid < 128) {
    float s = 0.f;
    for (int t = 0; t < L_CHK; ++t) s += Vs[t][tid - 64];
    vschunk[(size_t)blk * D_DIM + (tid - 64)] = s;
  }
}

// Exclusive prefix over chunks for the D*D state, per head. Fully unrolled so
// all 32 loads are in flight before the serial adds (latency: 32 RTs -> ~1).
__global__ __launch_bounds__(256) void scan_kv(
    const float* __restrict__ kvchunk, float* __restrict__ kvpref) {
  int gid = blockIdx.x * 256 + threadIdx.x;  // h*4096 + de
  int h = gid >> 12;
  int de = gid & 4095;
  float vals[NC];
#pragma unroll
  for (int c = 0; c < NC; ++c)
    vals[c] = kvchunk[((size_t)(h * NC + c) << 12) + de];
  float run = 0.f;
#pragma unroll
  for (int c = 0; c < NC; ++c) {
    kvpref[((size_t)(h * NC + c) << 12) + de] = run;
    run += vals[c];
  }
}

// Exclusive prefix over chunks for ksum/vsum vectors.
__global__ __launch_bounds__(256) void scan_vec(
    const float* __restrict__ kschunk, const float* __restrict__ vschunk,
    float* __restrict__ kspref, float* __restrict__ vspref) {
  int gid = blockIdx.x * 256 + threadIdx.x;  // h*64 + d (total 1024)
  int h = gid >> 6, d = gid & 63;
  float kv_[NC], vv_[NC];
#pragma unroll
  for (int c = 0; c < NC; ++c) {
    size_t idx = (size_t)(h * NC + c) * 64 + d;
    kv_[c] = kschunk[idx];
    vv_[c] = vschunk[idx];
  }
  float rk = 0.f, rv = 0.f;
#pragma unroll
  for (int c = 0; c < NC; ++c) {
    size_t idx = (size_t)(h * NC + c) * 64 + d;
    kspref[idx] = rk;
    vspref[idx] = rv;
    rk += kv_[c];
    rv += vv_[c];
  }
}

// ---------------------------------------------------------------------------
// Per-(head,chunk) output -> yh/yl fp16 split, (T, H*D) layout.
// 256 threads: r = tid&63 (row), g = tid>>6 (16-dim quarter).
// Phase 1: S[r][j] = (j<=r) ? 1 + q_r.k_j : 0  into LDS (stride 65).
// Phase 2: num = vsum_pref + q @ KVpref + S @ V; den = c*L + q.kspref +
//          rowsum(S).  KVpref staged into K's LDS after phase 1.
// ---------------------------------------------------------------------------
__global__ __launch_bounds__(256) void attn_out(
    const float* __restrict__ q, const float* __restrict__ k,
    const float* __restrict__ v, const float* __restrict__ kvpref,
    const float* __restrict__ kspref, const float* __restrict__ vspref,
    _Float16* __restrict__ yh, _Float16* __restrict__ yl) {
  __shared__ float Ks[L_CHK * D_DIM];       // phase1: K rows; phase2: KVpref
  __shared__ float Vs[L_CHK * D_DIM];
  __shared__ float Ss[L_CHK][L_CHK + 1];    // stride 65: column access free
  int blk = blockIdx.x;  // h*NC + c
  int h = blk / NC, c = blk % NC;
  int tid = threadIdx.x;
  int r = tid & 63;
  int g = tid >> 6;  // 0..3
  const size_t off = ((size_t)h * T_LEN + c * L_CHK) * D_DIM;
  // cooperative K,V load (coalesced float4)
#pragma unroll
  for (int m = 0; m < 4; ++m) {
    int el = (tid + m * 256) * 4;
    *(float4*)&Ks[el] = *(const float4*)&k[off + el];
    *(float4*)&Vs[el] = *(const float4*)&v[off + el];
  }
  // q row into registers (global; L1/L2-cached, read 4x per block)
  float qv[D_DIM];
#pragma unroll
  for (int i = 0; i < 16; ++i) {
    float4 t4 = *(const float4*)&q[off + r * D_DIM + i * 4];
    qv[i * 4 + 0] = t4.x; qv[i * 4 + 1] = t4.y;
    qv[i * 4 + 2] = t4.z; qv[i * 4 + 3] = t4.w;
  }
  __syncthreads();
  // Phase 1: this thread's 16 columns of S row-block
#pragma unroll
  for (int jj = 0; jj < 16; ++jj) {
    int j = g * 16 + jj;
    const float4* krow = (const float4*)&Ks[j * D_DIM];  // wave-broadcast
    float sdot = 0.f;
#pragma unroll
    for (int i = 0; i < 16; ++i) {
      float4 kj = krow[i];
      sdot += qv[i * 4] * kj.x + qv[i * 4 + 1] * kj.y + qv[i * 4 + 2] * kj.z +
              qv[i * 4 + 3] * kj.w;
    }
    Ss[r][j] = (j <= r) ? (sdot + 1.f) : 0.f;
  }
  __syncthreads();
  // Stage KVpref into Ks' LDS space (coalesced)
  const float* kvp = kvpref + (size_t)blk * (D_DIM * D_DIM);
#pragma unroll
  for (int m = 0; m < 4; ++m) {
    int el = (tid + m * 256) * 4;
    *(float4*)&Ks[el] = *(const float4*)&kvp[el];
  }
  __syncthreads();
  // Phase 2
  const float* ksp = kspref + (size_t)blk * D_DIM;
  const float* vsp = vspref + (size_t)blk * D_DIM;
  float den = (float)(c * L_CHK);  // rowsum(S) supplies the (r+1)
#pragma unroll
  for (int i = 0; i < 16; ++i) {
    float4 kk = *(const float4*)&ksp[i * 4];
    den += qv[i * 4] * kk.x + qv[i * 4 + 1] * kk.y + qv[i * 4 + 2] * kk.z +
           qv[i * 4 + 3] * kk.w;
  }
  float4 num[4];
#pragma unroll
  for (int i = 0; i < 4; ++i) num[i] = *(const float4*)&vsp[g * 16 + i * 4];
  // inter: num += q @ KVpref[:, g*16..g*16+15]  (LDS broadcast rows)
#pragma unroll
  for (int d = 0; d < D_DIM; ++d) {
    float qd = qv[d];
    const float4* kvrow = (const float4*)&Ks[d * D_DIM + g * 16];
#pragma unroll
    for (int i = 0; i < 4; ++i) {
      float4 k4 = kvrow[i];
      num[i].x += qd * k4.x; num[i].y += qd * k4.y;
      num[i].z += qd * k4.z; num[i].w += qd * k4.w;
    }
  }
  // intra: num += S[r][:] @ V[:, g-range]; rowsum for den
  float rs = 0.f;
#pragma unroll 8
  for (int j = 0; j < L_CHK; ++j) {
    float f = Ss[r][j];  // 2-way bank alias: free
    rs += f;
    const float4* vrow = (const float4*)&Vs[j * D_DIM + g * 16];
#pragma unroll
    for (int i = 0; i < 4; ++i) {
      float4 v4 = vrow[i];
      num[i].x += f * v4.x; num[i].y += f * v4.y;
      num[i].z += f * v4.z; num[i].w += f * v4.w;
    }
  }
  den += rs;
  float inv = 1.f / den;
  int t = c * L_CHK + r;
  size_t ybase = (size_t)t * (H_NUM * D_DIM) + h * D_DIM + g * 16;
#pragma unroll
  for (int i = 0; i < 4; ++i) {
    float o[4] = {num[i].x * inv, num[i].y * inv, num[i].z * inv,
                  num[i].w * inv};
    h4 hv, lv;
#pragma unroll
    for (int j = 0; j < 4; ++j) {
      _Float16 hh = (_Float16)o[j];
      hv[j] = hh;
      lv[j] = (_Float16)(o[j] - (float)hh);
    }
    *(h4*)&yh[ybase + i * 4] = hv;
    *(h4*)&yl[ybase + i * 4] = lv;
  }
}

// ---------------------------------------------------------------------------
extern "C" void kernel_launch(void* const* d_in, const int* in_sizes, int n_in,
                              void* d_out, int out_size, void* d_ws,
                              size_t ws_size, hipStream_t stream) {
  const float* x = (const float*)d_in[0];       // (1,2048,1024)
  const float* w_attn = (const float*)d_in[1];  // (3072,1024)
  const float* w_proj = (const float*)d_in[2];  // (1024,1024)
  const float* cosb = (const float*)d_in[3];    // (2048,64)
  const float* sinb = (const float*)d_in[4];    // (2048,64)
  float* out = (float*)d_out;                   // (2048,1024)

  char* ws = (char*)d_ws;
  // Region A (0..24MB): qkv fp32 (live GEMM->rope); then kvchunk/kvpref.
  float* qkv = (float*)ws;
  float* kvchunk = (float*)ws;                       // 8 MB  (after rope)
  float* kvpref = (float*)(ws + 8388608);            // 8 MB
  // Region B (24..48MB): q/k/v fp32
  float* qbuf = (float*)(ws + 25165824);
  float* kbuf = (float*)(ws + 25165824 + 8388608);
  float* vbuf = (float*)(ws + 25165824 + 16777216);
  // Region C (48..56MB): xh/xl (live split->QKV GEMM); then yh/yl.
  _Float16* xh = (_Float16*)(ws + 50331648);
  _Float16* xl = (_Float16*)(ws + 50331648 + 4194304);
  _Float16* yh = (_Float16*)(ws + 50331648);
  _Float16* yl = (_Float16*)(ws + 50331648 + 4194304);
  // Region D (56..68MB): wah/wal (live split->QKV GEMM); then scan vectors.
  _Float16* wah = (_Float16*)(ws + 58720256);
  _Float16* wal = (_Float16*)(ws + 58720256 + 6291456);
  float* kschunk = (float*)(ws + 58720256);
  float* vschunk = (float*)(ws + 58720256 + 131072);
  float* kspref = (float*)(ws + 58720256 + 262144);
  float* vspref = (float*)(ws + 58720256 + 393216);
  // Region E (68..72MB): wph/wpl (live whole call).
  _Float16* wph = (_Float16*)(ws + 71303168);
  _Float16* wpl = (_Float16*)(ws + 71303168 + 2097152);

  // 0) splits: x*64, w_attn*64, w_proj*64 (pow2 scales; undone in epilogues)
  split_f16<<<(T_LEN * C_DIM / 8 + 255) / 256, 256, 0, stream>>>(
      x, xh, xl, T_LEN * C_DIM, 64.f);
  split_f16<<<(QKV_N * C_DIM / 8 + 255) / 256, 256, 0, stream>>>(
      w_attn, wah, wal, QKV_N * C_DIM, 64.f);
  split_f16<<<(C_DIM * C_DIM / 8 + 255) / 256, 256, 0, stream>>>(
      w_proj, wph, wpl, C_DIM * C_DIM, 64.f);

  // 1) qkv = x @ w_attn^T : M=2048, N=3072, K=1024; scale 2^-12
  {
    dim3 grid(QKV_N / 128, T_LEN / 128);
    gemm_nt_f16x3<<<grid, 256, 0, stream>>>(xh, xl, wah, wal, qkv, T_LEN,
                                            QKV_N, C_DIM, 1.f / 4096.f);
  }
  // 2) rope + split
  rope_split<<<(H_NUM * T_LEN * D_DIM) / 256, 256, 0, stream>>>(
      qkv, cosb, sinb, qbuf, kbuf, vbuf);
  // 3) per-chunk sums (region A/D reused from here)
  chunk_kv<<<H_NUM * NC, 256, 0, stream>>>(kbuf, vbuf, kvchunk, kschunk,
                                           vschunk);
  // 4) prefix scans
  scan_kv<<<(H_NUM * D_DIM * D_DIM) / 256, 256, 0, stream>>>(kvchunk, kvpref);
  scan_vec<<<(H_NUM * D_DIM) / 256, 256, 0, stream>>>(kschunk, vschunk, kspref,
                                                      vspref);
  // 5) attention output -> yh/yl (T, H*D) fp16-split (fused, no extra pass)
  attn_out<<<H_NUM * NC, 256, 0, stream>>>(qbuf, kbuf, vbuf, kvpref, kspref,
                                           vspref, yh, yl);
  // 6) out = y @ w_proj^T : M=2048, N=1024, K=1024; scale 2^-6
  {
    dim3 grid(C_DIM / 128, T_LEN / 128);
    gemm_nt_f16x3<<<grid, 256, 0, stream>>>(yh, yl, wph, wpl, out, T_LEN,
                                            C_DIM, C_DIM, 1.f / 64.f);
  }
}

// Round 5
// 202.375 us; speedup vs baseline: 2.7135x; 1.1229x over previous
//
#include <hip/hip_runtime.h>

// Problem constants (B=1)
#define T_LEN 2048
#define C_DIM 1024
#define H_NUM 16
#define D_DIM 64
#define QKV_N (3 * H_NUM * D_DIM)   // 3072
#define L_CHK 64
#define NC (T_LEN / L_CHK)          // 32

typedef _Float16 h8 __attribute__((ext_vector_type(8)));
typedef _Float16 h4 __attribute__((ext_vector_type(4)));
typedef float f32x4 __attribute__((ext_vector_type(4)));

// ---------------------------------------------------------------------------
// Fused fp32 -> (hi,lo) fp16 split for all three inputs, scale 64.
// 8 elems/thread. Region sizes: x 2M, w_attn 3M, w_proj 1M elems.
// ---------------------------------------------------------------------------
__global__ __launch_bounds__(256) void split3_f16(
    const float* __restrict__ x, _Float16* __restrict__ xh,
    _Float16* __restrict__ xl, const float* __restrict__ wa,
    _Float16* __restrict__ wah, _Float16* __restrict__ wal,
    const float* __restrict__ wp, _Float16* __restrict__ wph,
    _Float16* __restrict__ wpl) {
  int i = (blockIdx.x * 256 + threadIdx.x) * 8;
  const float* src;
  _Float16 *dh, *dl;
  int base;
  if (i < 2097152) {
    src = x; dh = xh; dl = xl; base = i;
  } else if (i < 2097152 + 3145728) {
    src = wa; dh = wah; dl = wal; base = i - 2097152;
  } else {
    src = wp; dh = wph; dl = wpl; base = i - 5242880;
  }
  float4 a = *(const float4*)(src + base);
  float4 b = *(const float4*)(src + base + 4);
  float v[8] = {a.x, a.y, a.z, a.w, b.x, b.y, b.z, b.w};
  h8 hv, lv;
#pragma unroll
  for (int j = 0; j < 8; ++j) {
    float s = v[j] * 64.f;
    _Float16 h = (_Float16)s;
    hv[j] = h;
    lv[j] = (_Float16)(s - (float)h);
  }
  *(h8*)(dh + base) = hv;
  *(h8*)(dl + base) = lv;
}

// ---------------------------------------------------------------------------
// Split-precision fp16 NT MFMA GEMM: C = outscale * (A*B^T),
// A ~ Ah+Al, B ~ Bh+Bl; acc += Ah*Bh + Ah*Bl + Al*Bh (3 MFMAs, fp32 acc).
// Tile BM=64 x BN (128 or 64), BK=32, 256 thr = 2x2 waves of 32 x BN/2.
// Staging via global_load_lds width=16, unpadded [rows][32] LDS.
// ---------------------------------------------------------------------------
template <int BN>
__global__ __launch_bounds__(256) void gemm_nt_f16x3(
    const _Float16* __restrict__ Ah, const _Float16* __restrict__ Al,
    const _Float16* __restrict__ Bh, const _Float16* __restrict__ Bl,
    float* __restrict__ C, int M, int N, int K, float outscale) {
  constexpr int NJ = BN / 32;  // N-tiles per wave
  __shared__ _Float16 sAh[64 * 32];
  __shared__ _Float16 sAl[64 * 32];
  __shared__ _Float16 sBh[BN * 32];
  __shared__ _Float16 sBl[BN * 32];
  const int tid = threadIdx.x;
  const int wave = tid >> 6;
  const int lane = tid & 63;
  const int bm = blockIdx.y * 64;
  const int bn = blockIdx.x * BN;
  const int wm = wave >> 1;          // 0..1 -> 32-row half
  const int wn = wave & 1;           // 0..1 -> BN/2-col half
  const int srow = lane >> 2;        // 0..15 staging row within chunk
  const int scol = (lane & 3) * 8;   // staging col (halves)
  const int quad = lane >> 4;        // 0..3
  const int lrow = lane & 15;

  f32x4 acc[2][NJ];
#pragma unroll
  for (int i = 0; i < 2; ++i)
#pragma unroll
    for (int j = 0; j < NJ; ++j) acc[i][j] = (f32x4){0.f, 0.f, 0.f, 0.f};

  for (int k0 = 0; k0 < K; k0 += 32) {
    // stage A: 4 chunks of 16 rows, one per wave, per array
    {
      const int row = wave * 16 + srow;
      const _Float16* ga = Ah + (size_t)(bm + row) * K + k0 + scol;
      const _Float16* gb = Al + (size_t)(bm + row) * K + k0 + scol;
      __builtin_amdgcn_global_load_lds(
          (const __attribute__((address_space(1))) void*)ga,
          (__attribute__((address_space(3))) void*)(sAh + wave * 512), 16, 0,
          0);
      __builtin_amdgcn_global_load_lds(
          (const __attribute__((address_space(1))) void*)gb,
          (__attribute__((address_space(3))) void*)(sAl + wave * 512), 16, 0,
          0);
    }
    // stage B: BN/16 chunks, BN/64 per wave, per array
#pragma unroll
    for (int it = 0; it < BN / 64; ++it) {
      const int chunk = wave + it * 4;
      const int row = chunk * 16 + srow;
      const _Float16* ga = Bh + (size_t)(bn + row) * K + k0 + scol;
      const _Float16* gb = Bl + (size_t)(bn + row) * K + k0 + scol;
      __builtin_amdgcn_global_load_lds(
          (const __attribute__((address_space(1))) void*)ga,
          (__attribute__((address_space(3))) void*)(sBh + chunk * 512), 16, 0,
          0);
      __builtin_amdgcn_global_load_lds(
          (const __attribute__((address_space(1))) void*)gb,
          (__attribute__((address_space(3))) void*)(sBl + chunk * 512), 16, 0,
          0);
    }
    __syncthreads();
    h8 ah[2], al[2], bh[NJ], bl[NJ];
#pragma unroll
    for (int i = 0; i < 2; ++i) {
      const int ra = (wm * 32 + i * 16 + lrow) * 32 + quad * 8;
      ah[i] = *(const h8*)&sAh[ra];
      al[i] = *(const h8*)&sAl[ra];
    }
#pragma unroll
    for (int j = 0; j < NJ; ++j) {
      const int rb = (wn * (BN / 2) + j * 16 + lrow) * 32 + quad * 8;
      bh[j] = *(const h8*)&sBh[rb];
      bl[j] = *(const h8*)&sBl[rb];
    }
#pragma unroll
    for (int i = 0; i < 2; ++i)
#pragma unroll
      for (int j = 0; j < NJ; ++j) {
        acc[i][j] = __builtin_amdgcn_mfma_f32_16x16x32_f16(ah[i], bh[j],
                                                           acc[i][j], 0, 0, 0);
        acc[i][j] = __builtin_amdgcn_mfma_f32_16x16x32_f16(ah[i], bl[j],
                                                           acc[i][j], 0, 0, 0);
        acc[i][j] = __builtin_amdgcn_mfma_f32_16x16x32_f16(al[i], bh[j],
                                                           acc[i][j], 0, 0, 0);
      }
    __syncthreads();
  }
  // epilogue: C/D layout col=lane&15, row=quad*4+reg
#pragma unroll
  for (int i = 0; i < 2; ++i) {
    const int rbase = bm + wm * 32 + i * 16 + quad * 4;
#pragma unroll
    for (int j = 0; j < NJ; ++j) {
      const int col = bn + wn * (BN / 2) + j * 16 + lrow;
#pragma unroll
      for (int r = 0; r < 4; ++r)
        C[(size_t)(rbase + r) * N + col] = acc[i][j][r] * outscale;
    }
  }
}

// ---------------------------------------------------------------------------
// RoPE + split qkv (T,3072) -> q,k,v each [H][T][D]; rope on q,k only.
// ---------------------------------------------------------------------------
__global__ __launch_bounds__(256) void rope_split(
    const float* __restrict__ qkv, const float* __restrict__ cosb,
    const float* __restrict__ sinb, float* __restrict__ q,
    float* __restrict__ k, float* __restrict__ v) {
  int idx = blockIdx.x * 256 + threadIdx.x;  // == h*T*D + t*D + d
  int d = idx & 63;
  int t = (idx >> 6) & (T_LEN - 1);
  int h = idx >> 17;  // D*T = 2^17
  const float* base = qkv + (size_t)t * QKV_N + h * 3 * D_DIM;
  float c = cosb[t * D_DIM + d];
  float s = sinb[t * D_DIM + d];
  float qv = base[d];
  float kv = base[D_DIM + d];
  float vv = base[2 * D_DIM + d];
  float qr = (d < 32) ? -base[d + 32] : base[d - 32];
  float kr = (d < 32) ? -base[D_DIM + d + 32] : base[D_DIM + d - 32];
  q[idx] = qv * c + qr * s;
  k[idx] = kv * c + kr * s;
  v[idx] = vv;
}

// ---------------------------------------------------------------------------
// Per-(head,chunk) sums: kv[d][e], ksum[d], vsum[d]. One block per (h,c).
// ---------------------------------------------------------------------------
__global__ __launch_bounds__(256) void chunk_kv(
    const float* __restrict__ k, const float* __restrict__ v,
    float* __restrict__ kvchunk, float* __restrict__ kschunk,
    float* __restrict__ vschunk) {
  __shared__ float Ks[L_CHK][D_DIM];
  __shared__ float Vs[L_CHK][D_DIM];
  int blk = blockIdx.x;  // h*NC + c
  const size_t off = ((size_t)(blk / NC) * T_LEN + (blk % NC) * L_CHK) * D_DIM;
  int tid = threadIdx.x;
#pragma unroll
  for (int m = 0; m < 4; ++m) {
    int el = (tid + m * 256) * 4;
    *(float4*)&((float*)Ks)[el] = *(const float4*)&k[off + el];
    *(float4*)&((float*)Vs)[el] = *(const float4*)&v[off + el];
  }
  __syncthreads();
  int e = tid & 63;
  int q2 = tid >> 6;  // 0..3
  float acc[16] = {};
  for (int t = 0; t < L_CHK; ++t) {
    float ve = Vs[t][e];
#pragma unroll
    for (int m = 0; m < 16; ++m) acc[m] += Ks[t][q2 * 16 + m] * ve;
  }
  float* outb = kvchunk + (size_t)blk * (D_DIM * D_DIM);
#pragma unroll
  for (int m = 0; m < 16; ++m) outb[(q2 * 16 + m) * D_DIM + e] = acc[m];
  if (tid < 64) {
    float s = 0.f;
    for (int t = 0; t < L_CHK; ++t) s += Ks[t][tid];
    kschunk[(size_t)blk * D_DIM + tid] = s;
  } else if (tid < 128) {
    float s = 0.f;
    for (int t = 0; t < L_CHK; ++t) s += Vs[t][tid - 64];
    vschunk[(size_t)blk * D_DIM + (tid - 64)] = s;
  }
}

// Exclusive prefix over chunks for the D*D state, per head. Fully unrolled so
// all 32 loads are in flight before the serial adds.
__global__ __launch_bounds__(256) void scan_kv(
    const float* __restrict__ kvchunk, float* __restrict__ kvpref) {
  int gid = blockIdx.x * 256 + threadIdx.x;  // h*4096 + de
  int h = gid >> 12;
  int de = gid & 4095;
  float vals[NC];
#pragma unroll
  for (int c = 0; c < NC; ++c)
    vals[c] = kvchunk[((size_t)(h * NC + c) << 12) + de];
  float run = 0.f;
#pragma unroll
  for (int c = 0; c < NC; ++c) {
    kvpref[((size_t)(h * NC + c) << 12) + de] = run;
    run += vals[c];
  }
}

// Exclusive prefix over chunks for ksum/vsum vectors.
__global__ __launch_bounds__(256) void scan_vec(
    const float* __restrict__ kschunk, const float* __restrict__ vschunk,
    float* __restrict__ kspref, float* __restrict__ vspref) {
  int gid = blockIdx.x * 256 + threadIdx.x;  // h*64 + d (total 1024)
  int h = gid >> 6, d = gid & 63;
  float kv_[NC], vv_[NC];
#pragma unroll
  for (int c = 0; c < NC; ++c) {
    size_t idx = (size_t)(h * NC + c) * 64 + d;
    kv_[c] = kschunk[idx];
    vv_[c] = vschunk[idx];
  }
  float rk = 0.f, rv = 0.f;
#pragma unroll
  for (int c = 0; c < NC; ++c) {
    size_t idx = (size_t)(h * NC + c) * 64 + d;
    kspref[idx] = rk;
    vspref[idx] = rv;
    rk += kv_[c];
    rv += vv_[c];
  }
}

// ---------------------------------------------------------------------------
// Per-(head,chunk) output -> yh/yl fp16 split, (T, H*D) layout.
// 256 threads: r = tid&63 (row), g = tid>>6 (16-dim quarter).
// ---------------------------------------------------------------------------
__global__ __launch_bounds__(256) void attn_out(
    const float* __restrict__ q, const float* __restrict__ k,
    const float* __restrict__ v, const float* __restrict__ kvpref,
    const float* __restrict__ kspref, const float* __restrict__ vspref,
    _Float16* __restrict__ yh, _Float16* __restrict__ yl) {
  __shared__ float Ks[L_CHK * D_DIM];       // phase1: K rows; phase2: KVpref
  __shared__ float Vs[L_CHK * D_DIM];
  __shared__ float Ss[L_CHK][L_CHK + 1];    // stride 65: column access free
  int blk = blockIdx.x;  // h*NC + c
  int h = blk / NC, c = blk % NC;
  int tid = threadIdx.x;
  int r = tid & 63;
  int g = tid >> 6;  // 0..3
  const size_t off = ((size_t)h * T_LEN + c * L_CHK) * D_DIM;
#pragma unroll
  for (int m = 0; m < 4; ++m) {
    int el = (tid + m * 256) * 4;
    *(float4*)&Ks[el] = *(const float4*)&k[off + el];
    *(float4*)&Vs[el] = *(const float4*)&v[off + el];
  }
  float qv[D_DIM];
#pragma unroll
  for (int i = 0; i < 16; ++i) {
    float4 t4 = *(const float4*)&q[off + r * D_DIM + i * 4];
    qv[i * 4 + 0] = t4.x; qv[i * 4 + 1] = t4.y;
    qv[i * 4 + 2] = t4.z; qv[i * 4 + 3] = t4.w;
  }
  __syncthreads();
#pragma unroll
  for (int jj = 0; jj < 16; ++jj) {
    int j = g * 16 + jj;
    const float4* krow = (const float4*)&Ks[j * D_DIM];  // wave-broadcast
    float sdot = 0.f;
#pragma unroll
    for (int i = 0; i < 16; ++i) {
      float4 kj = krow[i];
      sdot += qv[i * 4] * kj.x + qv[i * 4 + 1] * kj.y + qv[i * 4 + 2] * kj.z +
              qv[i * 4 + 3] * kj.w;
    }
    Ss[r][j] = (j <= r) ? (sdot + 1.f) : 0.f;
  }
  __syncthreads();
  const float* kvp = kvpref + (size_t)blk * (D_DIM * D_DIM);
#pragma unroll
  for (int m = 0; m < 4; ++m) {
    int el = (tid + m * 256) * 4;
    *(float4*)&Ks[el] = *(const float4*)&kvp[el];
  }
  __syncthreads();
  const float* ksp = kspref + (size_t)blk * D_DIM;
  const float* vsp = vspref + (size_t)blk * D_DIM;
  float den = (float)(c * L_CHK);  // rowsum(S) supplies the (r+1)
#pragma unroll
  for (int i = 0; i < 16; ++i) {
    float4 kk = *(const float4*)&ksp[i * 4];
    den += qv[i * 4] * kk.x + qv[i * 4 + 1] * kk.y + qv[i * 4 + 2] * kk.z +
           qv[i * 4 + 3] * kk.w;
  }
  float4 num[4];
#pragma unroll
  for (int i = 0; i < 4; ++i) num[i] = *(const float4*)&vsp[g * 16 + i * 4];
#pragma unroll
  for (int d = 0; d < D_DIM; ++d) {
    float qd = qv[d];
    const float4* kvrow = (const float4*)&Ks[d * D_DIM + g * 16];
#pragma unroll
    for (int i = 0; i < 4; ++i) {
      float4 k4 = kvrow[i];
      num[i].x += qd * k4.x; num[i].y += qd * k4.y;
      num[i].z += qd * k4.z; num[i].w += qd * k4.w;
    }
  }
  float rs = 0.f;
#pragma unroll 8
  for (int j = 0; j < L_CHK; ++j) {
    float f = Ss[r][j];
    rs += f;
    const float4* vrow = (const float4*)&Vs[j * D_DIM + g * 16];
#pragma unroll
    for (int i = 0; i < 4; ++i) {
      float4 v4 = vrow[i];
      num[i].x += f * v4.x; num[i].y += f * v4.y;
      num[i].z += f * v4.z; num[i].w += f * v4.w;
    }
  }
  den += rs;
  float inv = 1.f / den;
  int t = c * L_CHK + r;
  size_t ybase = (size_t)t * (H_NUM * D_DIM) + h * D_DIM + g * 16;
#pragma unroll
  for (int i = 0; i < 4; ++i) {
    float o[4] = {num[i].x * inv, num[i].y * inv, num[i].z * inv,
                  num[i].w * inv};
    h4 hv, lv;
#pragma unroll
    for (int j = 0; j < 4; ++j) {
      _Float16 hh = (_Float16)o[j];
      hv[j] = hh;
      lv[j] = (_Float16)(o[j] - (float)hh);
    }
    *(h4*)&yh[ybase + i * 4] = hv;
    *(h4*)&yl[ybase + i * 4] = lv;
  }
}

// ---------------------------------------------------------------------------
extern "C" void kernel_launch(void* const* d_in, const int* in_sizes, int n_in,
                              void* d_out, int out_size, void* d_ws,
                              size_t ws_size, hipStream_t stream) {
  const float* x = (const float*)d_in[0];       // (1,2048,1024)
  const float* w_attn = (const float*)d_in[1];  // (3072,1024)
  const float* w_proj = (const float*)d_in[2];  // (1024,1024)
  const float* cosb = (const float*)d_in[3];    // (2048,64)
  const float* sinb = (const float*)d_in[4];    // (2048,64)
  float* out = (float*)d_out;                   // (2048,1024)

  char* ws = (char*)d_ws;
  // Region A (0..24MB): qkv fp32 (live GEMM->rope); then kvchunk/kvpref.
  float* qkv = (float*)ws;
  float* kvchunk = (float*)ws;                       // 8 MB  (after rope)
  float* kvpref = (float*)(ws + 8388608);            // 8 MB
  // Region B (24..48MB): q/k/v fp32
  float* qbuf = (float*)(ws + 25165824);
  float* kbuf = (float*)(ws + 25165824 + 8388608);
  float* vbuf = (float*)(ws + 25165824 + 16777216);
  // Region C (48..56MB): xh/xl (live split->QKV GEMM); then yh/yl.
  _Float16* xh = (_Float16*)(ws + 50331648);
  _Float16* xl = (_Float16*)(ws + 50331648 + 4194304);
  _Float16* yh = (_Float16*)(ws + 50331648);
  _Float16* yl = (_Float16*)(ws + 50331648 + 4194304);
  // Region D (56..68MB): wah/wal (live split->QKV GEMM); then scan vectors.
  _Float16* wah = (_Float16*)(ws + 58720256);
  _Float16* wal = (_Float16*)(ws + 58720256 + 6291456);
  float* kschunk = (float*)(ws + 58720256);
  float* vschunk = (float*)(ws + 58720256 + 131072);
  float* kspref = (float*)(ws + 58720256 + 262144);
  float* vspref = (float*)(ws + 58720256 + 393216);
  // Region E (68..72MB): wph/wpl (live whole call).
  _Float16* wph = (_Float16*)(ws + 71303168);
  _Float16* wpl = (_Float16*)(ws + 71303168 + 2097152);

  // 0) fused splits: x, w_attn, w_proj, all scale 64 (undone in epilogues)
  split3_f16<<<3072, 256, 0, stream>>>(x, xh, xl, w_attn, wah, wal, w_proj,
                                       wph, wpl);

  // 1) qkv = x @ w_attn^T : M=2048, N=3072, K=1024; scale 2^-12
  {
    dim3 grid(QKV_N / 128, T_LEN / 64);   // 24 x 32 = 768 blocks
    gemm_nt_f16x3<128><<<grid, 256, 0, stream>>>(xh, xl, wah, wal, qkv, T_LEN,
                                                 QKV_N, C_DIM, 1.f / 4096.f);
  }
  // 2) rope + split
  rope_split<<<(H_NUM * T_LEN * D_DIM) / 256, 256, 0, stream>>>(
      qkv, cosb, sinb, qbuf, kbuf, vbuf);
  // 3) per-chunk sums (region A/D reused from here)
  chunk_kv<<<H_NUM * NC, 256, 0, stream>>>(kbuf, vbuf, kvchunk, kschunk,
                                           vschunk);
  // 4) prefix scans
  scan_kv<<<(H_NUM * D_DIM * D_DIM) / 256, 256, 0, stream>>>(kvchunk, kvpref);
  scan_vec<<<(H_NUM * D_DIM) / 256, 256, 0, stream>>>(kschunk, vschunk, kspref,
                                                      vspref);
  // 5) attention output -> yh/yl (T, H*D) fp16-split
  attn_out<<<H_NUM * NC, 256, 0, stream>>>(qbuf, kbuf, vbuf, kvpref, kspref,
                                           vspref, yh, yl);
  // 6) out = y @ w_proj^T : M=2048, N=1024, K=1024; scale 2^-6
  {
    dim3 grid(C_DIM / 64, T_LEN / 64);    // 16 x 32 = 512 blocks
    gemm_nt_f16x3<64><<<grid, 256, 0, stream>>>(yh, yl, wph, wpl, out, T_LEN,
                                                C_DIM, C_DIM, 1.f / 64.f);
  }
}

// Round 6
// 193.858 us; speedup vs baseline: 2.8327x; 1.0439x over previous
//
#include <hip/hip_runtime.h>

// Problem constants (B=1)
#define T_LEN 2048
#define C_DIM 1024
#define H_NUM 16
#define D_DIM 64
#define QKV_N (3 * H_NUM * D_DIM)   // 3072
#define L_CHK 64
#define NC (T_LEN / L_CHK)          // 32

typedef _Float16 h8 __attribute__((ext_vector_type(8)));
typedef _Float16 h4 __attribute__((ext_vector_type(4)));
typedef float f32x4 __attribute__((ext_vector_type(4)));

// ---------------------------------------------------------------------------
// Fused fp32 -> (hi,lo) fp16 split for all three inputs, scale 64.
// ---------------------------------------------------------------------------
__global__ __launch_bounds__(256) void split3_f16(
    const float* __restrict__ x, _Float16* __restrict__ xh,
    _Float16* __restrict__ xl, const float* __restrict__ wa,
    _Float16* __restrict__ wah, _Float16* __restrict__ wal,
    const float* __restrict__ wp, _Float16* __restrict__ wph,
    _Float16* __restrict__ wpl) {
  int i = (blockIdx.x * 256 + threadIdx.x) * 8;
  const float* src;
  _Float16 *dh, *dl;
  int base;
  if (i < 2097152) {
    src = x; dh = xh; dl = xl; base = i;
  } else if (i < 2097152 + 3145728) {
    src = wa; dh = wah; dl = wal; base = i - 2097152;
  } else {
    src = wp; dh = wph; dl = wpl; base = i - 5242880;
  }
  float4 a = *(const float4*)(src + base);
  float4 b = *(const float4*)(src + base + 4);
  float v[8] = {a.x, a.y, a.z, a.w, b.x, b.y, b.z, b.w};
  h8 hv, lv;
#pragma unroll
  for (int j = 0; j < 8; ++j) {
    float s = v[j] * 64.f;
    _Float16 h = (_Float16)s;
    hv[j] = h;
    lv[j] = (_Float16)(s - (float)h);
  }
  *(h8*)(dh + base) = hv;
  *(h8*)(dl + base) = lv;
}

// ---------------------------------------------------------------------------
// Split-precision fp16 NT MFMA GEMM, optionally with fused RoPE+qkv-split
// epilogue. C = outscale*(A*B^T); acc += Ah*Bh + Ah*Bl + Al*Bh.
// Tile BM=64 x BN, BK=32, 256 thr = 2x2 waves of 32 x BN/2.
// ROPE path (BN=128, N=3072): each wave's 64-col span is exactly one q/k/v
// 64-dim block of one head (192 = 3*64). Rotate pairing d<->d+-32 is
// acc[i][j]<->acc[i][j+-2] (lane-local). cos/sin tiles staged into the dead
// staging LDS after the K-loop. Writes q/k/v [H][T][D] fp32 directly.
// ---------------------------------------------------------------------------
template <int BN, bool ROPE>
__global__ __launch_bounds__(256) void gemm_nt_f16x3(
    const _Float16* __restrict__ Ah, const _Float16* __restrict__ Al,
    const _Float16* __restrict__ Bh, const _Float16* __restrict__ Bl,
    float* __restrict__ C, const float* __restrict__ cosb,
    const float* __restrict__ sinb, float* __restrict__ qout,
    float* __restrict__ kout, float* __restrict__ vout, int M, int N, int K,
    float outscale) {
  constexpr int NJ = BN / 32;  // N-tiles per wave
  constexpr int GEMM_BYTES = (64 * 32 * 2 + BN * 32 * 2) * 2;  // hi+lo
  constexpr int ROPE_BYTES = ROPE ? (2 * 64 * 64 * 4) : 0;     // cos+sin
  constexpr int SMEM_BYTES = GEMM_BYTES > ROPE_BYTES ? GEMM_BYTES : ROPE_BYTES;
  __shared__ __align__(16) char smem[SMEM_BYTES];
  _Float16* sAh = (_Float16*)smem;
  _Float16* sAl = sAh + 64 * 32;
  _Float16* sBh = sAl + 64 * 32;
  _Float16* sBl = sBh + BN * 32;
  const int tid = threadIdx.x;
  const int wave = tid >> 6;
  const int lane = tid & 63;
  const int bm = blockIdx.y * 64;
  const int bn = blockIdx.x * BN;
  const int wm = wave >> 1;          // 0..1 -> 32-row half
  const int wn = wave & 1;           // 0..1 -> BN/2-col half
  const int srow = lane >> 2;        // staging row within chunk
  const int scol = (lane & 3) * 8;   // staging col (halves)
  const int quad = lane >> 4;        // 0..3
  const int lrow = lane & 15;

  f32x4 acc[2][NJ];
#pragma unroll
  for (int i = 0; i < 2; ++i)
#pragma unroll
    for (int j = 0; j < NJ; ++j) acc[i][j] = (f32x4){0.f, 0.f, 0.f, 0.f};

  for (int k0 = 0; k0 < K; k0 += 32) {
    {
      const int row = wave * 16 + srow;
      const _Float16* ga = Ah + (size_t)(bm + row) * K + k0 + scol;
      const _Float16* gb = Al + (size_t)(bm + row) * K + k0 + scol;
      __builtin_amdgcn_global_load_lds(
          (const __attribute__((address_space(1))) void*)ga,
          (__attribute__((address_space(3))) void*)(sAh + wave * 512), 16, 0,
          0);
      __builtin_amdgcn_global_load_lds(
          (const __attribute__((address_space(1))) void*)gb,
          (__attribute__((address_space(3))) void*)(sAl + wave * 512), 16, 0,
          0);
    }
#pragma unroll
    for (int it = 0; it < BN / 64; ++it) {
      const int chunk = wave + it * 4;
      const int row = chunk * 16 + srow;
      const _Float16* ga = Bh + (size_t)(bn + row) * K + k0 + scol;
      const _Float16* gb = Bl + (size_t)(bn + row) * K + k0 + scol;
      __builtin_amdgcn_global_load_lds(
          (const __attribute__((address_space(1))) void*)ga,
          (__attribute__((address_space(3))) void*)(sBh + chunk * 512), 16, 0,
          0);
      __builtin_amdgcn_global_load_lds(
          (const __attribute__((address_space(1))) void*)gb,
          (__attribute__((address_space(3))) void*)(sBl + chunk * 512), 16, 0,
          0);
    }
    __syncthreads();
    h8 ah[2], al[2], bh[NJ], bl[NJ];
#pragma unroll
    for (int i = 0; i < 2; ++i) {
      const int ra = (wm * 32 + i * 16 + lrow) * 32 + quad * 8;
      ah[i] = *(const h8*)&sAh[ra];
      al[i] = *(const h8*)&sAl[ra];
    }
#pragma unroll
    for (int j = 0; j < NJ; ++j) {
      const int rb = (wn * (BN / 2) + j * 16 + lrow) * 32 + quad * 8;
      bh[j] = *(const h8*)&sBh[rb];
      bl[j] = *(const h8*)&sBl[rb];
    }
#pragma unroll
    for (int i = 0; i < 2; ++i)
#pragma unroll
      for (int j = 0; j < NJ; ++j) {
        acc[i][j] = __builtin_amdgcn_mfma_f32_16x16x32_f16(ah[i], bh[j],
                                                           acc[i][j], 0, 0, 0);
        acc[i][j] = __builtin_amdgcn_mfma_f32_16x16x32_f16(ah[i], bl[j],
                                                           acc[i][j], 0, 0, 0);
        acc[i][j] = __builtin_amdgcn_mfma_f32_16x16x32_f16(al[i], bh[j],
                                                           acc[i][j], 0, 0, 0);
      }
    __syncthreads();
  }
  // epilogue: C/D layout col=lane&15, row=quad*4+reg
  if constexpr (!ROPE) {
#pragma unroll
    for (int i = 0; i < 2; ++i) {
      const int rbase = bm + wm * 32 + i * 16 + quad * 4;
#pragma unroll
      for (int j = 0; j < NJ; ++j) {
        const int col = bn + wn * (BN / 2) + j * 16 + lrow;
#pragma unroll
        for (int r = 0; r < 4; ++r)
          C[(size_t)(rbase + r) * N + col] = acc[i][j][r] * outscale;
      }
    }
  } else {
    // stage cos/sin tiles for rows [bm, bm+64) -- contiguous 16 KB each
    float* cs = (float*)smem;
    float* sn = cs + 4096;
#pragma unroll
    for (int m = 0; m < 4; ++m) {
      int el = (tid + m * 256) * 4;
      *(float4*)&cs[el] = *(const float4*)&cosb[bm * D_DIM + el];
      *(float4*)&sn[el] = *(const float4*)&sinb[bm * D_DIM + el];
    }
    __syncthreads();
    const int colbase = bn + wn * 64;       // multiple of 64
    const int type = (colbase >> 6) % 3;    // 0=q, 1=k, 2=v
    const int head = colbase / 192;
    float* dst = (type == 0) ? qout : (type == 1) ? kout : vout;
    const size_t hbase = (size_t)head * T_LEN * D_DIM;
#pragma unroll
    for (int i = 0; i < 2; ++i) {
      const int tloc0 = wm * 32 + i * 16 + quad * 4;  // t - bm
#pragma unroll
      for (int r = 0; r < 4; ++r) {
        const int tloc = tloc0 + r;
        float* trow = dst + hbase + (size_t)(bm + tloc) * D_DIM;
#pragma unroll
        for (int j = 0; j < NJ; ++j) {
          const int d = j * 16 + lrow;
          float val = acc[i][j][r] * outscale;
          if (type < 2) {
            float rotv = ((j < 2) ? -acc[i][j + 2][r] : acc[i][j - 2][r]) *
                         outscale;
            val = val * cs[tloc * D_DIM + d] + rotv * sn[tloc * D_DIM + d];
          }
          trow[d] = val;
        }
      }
    }
  }
}

// ---------------------------------------------------------------------------
// Per-(head,chunk) sums: kv[d][e], ksum[d], vsum[d]. One block per (h,c).
// ---------------------------------------------------------------------------
__global__ __launch_bounds__(256) void chunk_kv(
    const float* __restrict__ k, const float* __restrict__ v,
    float* __restrict__ kvchunk, float* __restrict__ kschunk,
    float* __restrict__ vschunk) {
  __shared__ float Ks[L_CHK][D_DIM];
  __shared__ float Vs[L_CHK][D_DIM];
  int blk = blockIdx.x;  // h*NC + c
  const size_t off = ((size_t)(blk / NC) * T_LEN + (blk % NC) * L_CHK) * D_DIM;
  int tid = threadIdx.x;
#pragma unroll
  for (int m = 0; m < 4; ++m) {
    int el = (tid + m * 256) * 4;
    *(float4*)&((float*)Ks)[el] = *(const float4*)&k[off + el];
    *(float4*)&((float*)Vs)[el] = *(const float4*)&v[off + el];
  }
  __syncthreads();
  int e = tid & 63;
  int q2 = tid >> 6;  // 0..3
  float acc[16] = {};
  for (int t = 0; t < L_CHK; ++t) {
    float ve = Vs[t][e];
#pragma unroll
    for (int m = 0; m < 16; ++m) acc[m] += Ks[t][q2 * 16 + m] * ve;
  }
  float* outb = kvchunk + (size_t)blk * (D_DIM * D_DIM);
#pragma unroll
  for (int m = 0; m < 16; ++m) outb[(q2 * 16 + m) * D_DIM + e] = acc[m];
  if (tid < 64) {
    float s = 0.f;
    for (int t = 0; t < L_CHK; ++t) s += Ks[t][tid];
    kschunk[(size_t)blk * D_DIM + tid] = s;
  } else if (tid < 128) {
    float s = 0.f;
    for (int t = 0; t < L_CHK; ++t) s += Vs[t][tid - 64];
    vschunk[(size_t)blk * D_DIM + (tid - 64)] = s;
  }
}

// ---------------------------------------------------------------------------
// Fused exclusive prefix scans over chunks: blocks 0..255 do the D*D state,
// blocks 256..259 do the ksum/vsum vectors. Fully unrolled loads.
// ---------------------------------------------------------------------------
__global__ __launch_bounds__(256) void scan_fused(
    const float* __restrict__ kvchunk, float* __restrict__ kvpref,
    const float* __restrict__ kschunk, const float* __restrict__ vschunk,
    float* __restrict__ kspref, float* __restrict__ vspref) {
  int b = blockIdx.x;
  int tid = threadIdx.x;
  if (b < 256) {
    int gid = b * 256 + tid;  // h*4096 + de
    int h = gid >> 12;
    int de = gid & 4095;
    float vals[NC];
#pragma unroll
    for (int c = 0; c < NC; ++c)
      vals[c] = kvchunk[((size_t)(h * NC + c) << 12) + de];
    float run = 0.f;
#pragma unroll
    for (int c = 0; c < NC; ++c) {
      kvpref[((size_t)(h * NC + c) << 12) + de] = run;
      run += vals[c];
    }
  } else {
    int gid = (b - 256) * 256 + tid;  // h*64 + d (total 1024)
    int h = gid >> 6, d = gid & 63;
    float kv_[NC], vv_[NC];
#pragma unroll
    for (int c = 0; c < NC; ++c) {
      size_t idx = (size_t)(h * NC + c) * 64 + d;
      kv_[c] = kschunk[idx];
      vv_[c] = vschunk[idx];
    }
    float rk = 0.f, rv = 0.f;
#pragma unroll
    for (int c = 0; c < NC; ++c) {
      size_t idx = (size_t)(h * NC + c) * 64 + d;
      kspref[idx] = rk;
      vspref[idx] = rv;
      rk += kv_[c];
      rv += vv_[c];
    }
  }
}

// ---------------------------------------------------------------------------
// Per-(head,chunk) output -> yh/yl fp16 split, (T, H*D) layout.
// 256 threads: r = tid&63 (row), g = tid>>6 (16-dim quarter).
// ---------------------------------------------------------------------------
__global__ __launch_bounds__(256) void attn_out(
    const float* __restrict__ q, const float* __restrict__ k,
    const float* __restrict__ v, const float* __restrict__ kvpref,
    const float* __restrict__ kspref, const float* __restrict__ vspref,
    _Float16* __restrict__ yh, _Float16* __restrict__ yl) {
  __shared__ float Ks[L_CHK * D_DIM];       // phase1: K rows; phase2: KVpref
  __shared__ float Vs[L_CHK * D_DIM];
  __shared__ float Ss[L_CHK][L_CHK + 1];    // stride 65: column access free
  int blk = blockIdx.x;  // h*NC + c
  int h = blk / NC, c = blk % NC;
  int tid = threadIdx.x;
  int r = tid & 63;
  int g = tid >> 6;  // 0..3
  const size_t off = ((size_t)h * T_LEN + c * L_CHK) * D_DIM;
#pragma unroll
  for (int m = 0; m < 4; ++m) {
    int el = (tid + m * 256) * 4;
    *(float4*)&Ks[el] = *(const float4*)&k[off + el];
    *(float4*)&Vs[el] = *(const float4*)&v[off + el];
  }
  float qv[D_DIM];
#pragma unroll
  for (int i = 0; i < 16; ++i) {
    float4 t4 = *(const float4*)&q[off + r * D_DIM + i * 4];
    qv[i * 4 + 0] = t4.x; qv[i * 4 + 1] = t4.y;
    qv[i * 4 + 2] = t4.z; qv[i * 4 + 3] = t4.w;
  }
  __syncthreads();
#pragma unroll
  for (int jj = 0; jj < 16; ++jj) {
    int j = g * 16 + jj;
    const float4* krow = (const float4*)&Ks[j * D_DIM];  // wave-broadcast
    float sdot = 0.f;
#pragma unroll
    for (int i = 0; i < 16; ++i) {
      float4 kj = krow[i];
      sdot += qv[i * 4] * kj.x + qv[i * 4 + 1] * kj.y + qv[i * 4 + 2] * kj.z +
              qv[i * 4 + 3] * kj.w;
    }
    Ss[r][j] = (j <= r) ? (sdot + 1.f) : 0.f;
  }
  __syncthreads();
  const float* kvp = kvpref + (size_t)blk * (D_DIM * D_DIM);
#pragma unroll
  for (int m = 0; m < 4; ++m) {
    int el = (tid + m * 256) * 4;
    *(float4*)&Ks[el] = *(const float4*)&kvp[el];
  }
  __syncthreads();
  const float* ksp = kspref + (size_t)blk * D_DIM;
  const float* vsp = vspref + (size_t)blk * D_DIM;
  float den = (float)(c * L_CHK);  // rowsum(S) supplies the (r+1)
#pragma unroll
  for (int i = 0; i < 16; ++i) {
    float4 kk = *(const float4*)&ksp[i * 4];
    den += qv[i * 4] * kk.x + qv[i * 4 + 1] * kk.y + qv[i * 4 + 2] * kk.z +
           qv[i * 4 + 3] * kk.w;
  }
  float4 num[4];
#pragma unroll
  for (int i = 0; i < 4; ++i) num[i] = *(const float4*)&vsp[g * 16 + i * 4];
#pragma unroll
  for (int d = 0; d < D_DIM; ++d) {
    float qd = qv[d];
    const float4* kvrow = (const float4*)&Ks[d * D_DIM + g * 16];
#pragma unroll
    for (int i = 0; i < 4; ++i) {
      float4 k4 = kvrow[i];
      num[i].x += qd * k4.x; num[i].y += qd * k4.y;
      num[i].z += qd * k4.z; num[i].w += qd * k4.w;
    }
  }
  float rs = 0.f;
#pragma unroll 8
  for (int j = 0; j < L_CHK; ++j) {
    float f = Ss[r][j];
    rs += f;
    const float4* vrow = (const float4*)&Vs[j * D_DIM + g * 16];
#pragma unroll
    for (int i = 0; i < 4; ++i) {
      float4 v4 = vrow[i];
      num[i].x += f * v4.x; num[i].y += f * v4.y;
      num[i].z += f * v4.z; num[i].w += f * v4.w;
    }
  }
  den += rs;
  float inv = 1.f / den;
  int t = c * L_CHK + r;
  size_t ybase = (size_t)t * (H_NUM * D_DIM) + h * D_DIM + g * 16;
#pragma unroll
  for (int i = 0; i < 4; ++i) {
    float o[4] = {num[i].x * inv, num[i].y * inv, num[i].z * inv,
                  num[i].w * inv};
    h4 hv, lv;
#pragma unroll
    for (int j = 0; j < 4; ++j) {
      _Float16 hh = (_Float16)o[j];
      hv[j] = hh;
      lv[j] = (_Float16)(o[j] - (float)hh);
    }
    *(h4*)&yh[ybase + i * 4] = hv;
    *(h4*)&yl[ybase + i * 4] = lv;
  }
}

// ---------------------------------------------------------------------------
extern "C" void kernel_launch(void* const* d_in, const int* in_sizes, int n_in,
                              void* d_out, int out_size, void* d_ws,
                              size_t ws_size, hipStream_t stream) {
  const float* x = (const float*)d_in[0];       // (1,2048,1024)
  const float* w_attn = (const float*)d_in[1];  // (3072,1024)
  const float* w_proj = (const float*)d_in[2];  // (1024,1024)
  const float* cosb = (const float*)d_in[3];    // (2048,64)
  const float* sinb = (const float*)d_in[4];    // (2048,64)
  float* out = (float*)d_out;                   // (2048,1024)

  char* ws = (char*)d_ws;
  // Region A (0..16MB): kvchunk, kvpref
  float* kvchunk = (float*)ws;                       // 8 MB
  float* kvpref = (float*)(ws + 8388608);            // 8 MB
  // Region B (24..48MB): q/k/v fp32
  float* qbuf = (float*)(ws + 25165824);
  float* kbuf = (float*)(ws + 25165824 + 8388608);
  float* vbuf = (float*)(ws + 25165824 + 16777216);
  // Region C (48..56MB): xh/xl (live split->QKV GEMM); then yh/yl.
  _Float16* xh = (_Float16*)(ws + 50331648);
  _Float16* xl = (_Float16*)(ws + 50331648 + 4194304);
  _Float16* yh = (_Float16*)(ws + 50331648);
  _Float16* yl = (_Float16*)(ws + 50331648 + 4194304);
  // Region D (56..68MB): wah/wal (live split->QKV GEMM); then scan vectors.
  _Float16* wah = (_Float16*)(ws + 58720256);
  _Float16* wal = (_Float16*)(ws + 58720256 + 6291456);
  float* kschunk = (float*)(ws + 58720256);
  float* vschunk = (float*)(ws + 58720256 + 131072);
  float* kspref = (float*)(ws + 58720256 + 262144);
  float* vspref = (float*)(ws + 58720256 + 393216);
  // Region E (68..72MB): wph/wpl (live whole call).
  _Float16* wph = (_Float16*)(ws + 71303168);
  _Float16* wpl = (_Float16*)(ws + 71303168 + 2097152);

  // 0) fused splits: x, w_attn, w_proj, all scale 64 (undone in epilogues)
  split3_f16<<<3072, 256, 0, stream>>>(x, xh, xl, w_attn, wah, wal, w_proj,
                                       wph, wpl);

  // 1) qkv GEMM + fused RoPE/split -> q,k,v [H][T][D] fp32; scale 2^-12
  {
    dim3 grid(QKV_N / 128, T_LEN / 64);   // 24 x 32 = 768 blocks
    gemm_nt_f16x3<128, true><<<grid, 256, 0, stream>>>(
        xh, xl, wah, wal, nullptr, cosb, sinb, qbuf, kbuf, vbuf, T_LEN, QKV_N,
        C_DIM, 1.f / 4096.f);
  }
  // 2) per-chunk sums
  chunk_kv<<<H_NUM * NC, 256, 0, stream>>>(kbuf, vbuf, kvchunk, kschunk,
                                           vschunk);
  // 3) fused prefix scans (256 blocks kv + 4 blocks vec)
  scan_fused<<<260, 256, 0, stream>>>(kvchunk, kvpref, kschunk, vschunk,
                                      kspref, vspref);
  // 4) attention output -> yh/yl (T, H*D) fp16-split
  attn_out<<<H_NUM * NC, 256, 0, stream>>>(qbuf, kbuf, vbuf, kvpref, kspref,
                                           vspref, yh, yl);
  // 5) out = y @ w_proj^T : M=2048, N=1024, K=1024; scale 2^-6
  {
    dim3 grid(C_DIM / 64, T_LEN / 64);    // 16 x 32 = 512 blocks
    gemm_nt_f16x3<64, false><<<grid, 256, 0, stream>>>(
        yh, yl, wph, wpl, out, nullptr, nullptr, nullptr, nullptr, nullptr,
        T_LEN, C_DIM, C_DIM, 1.f / 64.f);
  }
}

// Round 7
// 186.748 us; speedup vs baseline: 2.9405x; 1.0381x over previous
//
#include <hip/hip_runtime.h>

// Problem constants (B=1)
#define T_LEN 2048
#define C_DIM 1024
#define H_NUM 16
#define D_DIM 64
#define QKV_N (3 * H_NUM * D_DIM)   // 3072
#define L_CHK 64
#define NC (T_LEN / L_CHK)          // 32

typedef _Float16 h8 __attribute__((ext_vector_type(8)));
typedef _Float16 h4 __attribute__((ext_vector_type(4)));
typedef float f32x4 __attribute__((ext_vector_type(4)));

// ---------------------------------------------------------------------------
// Fused fp32 -> fp16 split, scale 64. x & w_attn get hi+lo; w_proj hi only
// (proj GEMM is post-singularity: fp16-single is plenty).
// ---------------------------------------------------------------------------
__global__ __launch_bounds__(256) void split3_f16(
    const float* __restrict__ x, _Float16* __restrict__ xh,
    _Float16* __restrict__ xl, const float* __restrict__ wa,
    _Float16* __restrict__ wah, _Float16* __restrict__ wal,
    const float* __restrict__ wp, _Float16* __restrict__ wph) {
  int i = (blockIdx.x * 256 + threadIdx.x) * 8;
  const float* src;
  _Float16 *dh, *dl = nullptr;
  int base;
  if (i < 2097152) {
    src = x; dh = xh; dl = xl; base = i;
  } else if (i < 2097152 + 3145728) {
    src = wa; dh = wah; dl = wal; base = i - 2097152;
  } else {
    src = wp; dh = wph; base = i - 5242880;
  }
  float4 a = *(const float4*)(src + base);
  float4 b = *(const float4*)(src + base + 4);
  float v[8] = {a.x, a.y, a.z, a.w, b.x, b.y, b.z, b.w};
  h8 hv, lv;
#pragma unroll
  for (int j = 0; j < 8; ++j) {
    float s = v[j] * 64.f;
    _Float16 h = (_Float16)s;
    hv[j] = h;
    lv[j] = (_Float16)(s - (float)h);
  }
  *(h8*)(dh + base) = hv;
  if (dl) *(h8*)(dl + base) = lv;
}

// ---------------------------------------------------------------------------
// fp16 NT MFMA GEMM. SPLIT3: A~Ah+Al, B~Bh+Bl, acc += Ah*Bh+Ah*Bl+Al*Bh
// (3 MFMAs, fp32 acc, fp32-grade result). !SPLIT3: plain fp16, 1 MFMA.
// Tile BM=64 x BN, BK=32, 256 thr = 2x2 waves of 32 x BN/2.
// ROPE epilogue (BN=128, N=3072): wave's 64-col span == one q/k/v 64-dim
// block of one head; rotate pairing d<->d+-32 is acc[i][j]<->acc[i][j+-2]
// (lane-local). cos/sin staged into dead staging LDS after the K-loop.
// ---------------------------------------------------------------------------
template <int BN, bool ROPE, bool SPLIT3>
__global__ __launch_bounds__(256) void gemm_nt_f16(
    const _Float16* __restrict__ Ah, const _Float16* __restrict__ Al,
    const _Float16* __restrict__ Bh, const _Float16* __restrict__ Bl,
    float* __restrict__ C, const float* __restrict__ cosb,
    const float* __restrict__ sinb, float* __restrict__ qout,
    float* __restrict__ kout, float* __restrict__ vout, int M, int N, int K,
    float outscale) {
  constexpr int NJ = BN / 32;  // N-tiles per wave
  constexpr int NARR = SPLIT3 ? 2 : 1;
  constexpr int GEMM_BYTES = (64 * 32 * 2 + BN * 32 * 2) * NARR;
  constexpr int ROPE_BYTES = ROPE ? (2 * 64 * 64 * 4) : 0;
  constexpr int SMEM_BYTES = GEMM_BYTES > ROPE_BYTES ? GEMM_BYTES : ROPE_BYTES;
  __shared__ __align__(16) char smem[SMEM_BYTES];
  _Float16* sAh = (_Float16*)smem;
  _Float16* sAl = sAh + 64 * 32;                       // SPLIT3 only
  _Float16* sBh = sAh + 64 * 32 * NARR;
  _Float16* sBl = sBh + BN * 32;                       // SPLIT3 only
  const int tid = threadIdx.x;
  const int wave = tid >> 6;
  const int lane = tid & 63;
  const int bm = blockIdx.y * 64;
  const int bn = blockIdx.x * BN;
  const int wm = wave >> 1;          // 0..1 -> 32-row half
  const int wn = wave & 1;           // 0..1 -> BN/2-col half
  const int srow = lane >> 2;        // staging row within chunk
  const int scol = (lane & 3) * 8;   // staging col (halves)
  const int quad = lane >> 4;        // 0..3
  const int lrow = lane & 15;

  f32x4 acc[2][NJ];
#pragma unroll
  for (int i = 0; i < 2; ++i)
#pragma unroll
    for (int j = 0; j < NJ; ++j) acc[i][j] = (f32x4){0.f, 0.f, 0.f, 0.f};

  for (int k0 = 0; k0 < K; k0 += 32) {
    {
      const int row = wave * 16 + srow;
      const _Float16* ga = Ah + (size_t)(bm + row) * K + k0 + scol;
      __builtin_amdgcn_global_load_lds(
          (const __attribute__((address_space(1))) void*)ga,
          (__attribute__((address_space(3))) void*)(sAh + wave * 512), 16, 0,
          0);
      if constexpr (SPLIT3) {
        const _Float16* gb = Al + (size_t)(bm + row) * K + k0 + scol;
        __builtin_amdgcn_global_load_lds(
            (const __attribute__((address_space(1))) void*)gb,
            (__attribute__((address_space(3))) void*)(sAl + wave * 512), 16, 0,
            0);
      }
    }
#pragma unroll
    for (int it = 0; it < BN / 64; ++it) {
      const int chunk = wave + it * 4;
      const int row = chunk * 16 + srow;
      const _Float16* ga = Bh + (size_t)(bn + row) * K + k0 + scol;
      __builtin_amdgcn_global_load_lds(
          (const __attribute__((address_space(1))) void*)ga,
          (__attribute__((address_space(3))) void*)(sBh + chunk * 512), 16, 0,
          0);
      if constexpr (SPLIT3) {
        const _Float16* gb = Bl + (size_t)(bn + row) * K + k0 + scol;
        __builtin_amdgcn_global_load_lds(
            (const __attribute__((address_space(1))) void*)gb,
            (__attribute__((address_space(3))) void*)(sBl + chunk * 512), 16,
            0, 0);
      }
    }
    __syncthreads();
    h8 ah[2], al[2], bh[NJ], bl[NJ];
#pragma unroll
    for (int i = 0; i < 2; ++i) {
      const int ra = (wm * 32 + i * 16 + lrow) * 32 + quad * 8;
      ah[i] = *(const h8*)&sAh[ra];
      if constexpr (SPLIT3) al[i] = *(const h8*)&sAl[ra];
    }
#pragma unroll
    for (int j = 0; j < NJ; ++j) {
      const int rb = (wn * (BN / 2) + j * 16 + lrow) * 32 + quad * 8;
      bh[j] = *(const h8*)&sBh[rb];
      if constexpr (SPLIT3) bl[j] = *(const h8*)&sBl[rb];
    }
#pragma unroll
    for (int i = 0; i < 2; ++i)
#pragma unroll
      for (int j = 0; j < NJ; ++j) {
        acc[i][j] = __builtin_amdgcn_mfma_f32_16x16x32_f16(ah[i], bh[j],
                                                           acc[i][j], 0, 0, 0);
        if constexpr (SPLIT3) {
          acc[i][j] = __builtin_amdgcn_mfma_f32_16x16x32_f16(
              ah[i], bl[j], acc[i][j], 0, 0, 0);
          acc[i][j] = __builtin_amdgcn_mfma_f32_16x16x32_f16(
              al[i], bh[j], acc[i][j], 0, 0, 0);
        }
      }
    __syncthreads();
  }
  // epilogue: C/D layout col=lane&15, row=quad*4+reg
  if constexpr (!ROPE) {
#pragma unroll
    for (int i = 0; i < 2; ++i) {
      const int rbase = bm + wm * 32 + i * 16 + quad * 4;
#pragma unroll
      for (int j = 0; j < NJ; ++j) {
        const int col = bn + wn * (BN / 2) + j * 16 + lrow;
#pragma unroll
        for (int r = 0; r < 4; ++r)
          C[(size_t)(rbase + r) * N + col] = acc[i][j][r] * outscale;
      }
    }
  } else {
    float* cs = (float*)smem;
    float* sn = cs + 4096;
#pragma unroll
    for (int m = 0; m < 4; ++m) {
      int el = (tid + m * 256) * 4;
      *(float4*)&cs[el] = *(const float4*)&cosb[bm * D_DIM + el];
      *(float4*)&sn[el] = *(const float4*)&sinb[bm * D_DIM + el];
    }
    __syncthreads();
    const int colbase = bn + wn * 64;       // multiple of 64
    const int type = (colbase >> 6) % 3;    // 0=q, 1=k, 2=v
    const int head = colbase / 192;
    float* dst = (type == 0) ? qout : (type == 1) ? kout : vout;
    const size_t hbase = (size_t)head * T_LEN * D_DIM;
#pragma unroll
    for (int i = 0; i < 2; ++i) {
      const int tloc0 = wm * 32 + i * 16 + quad * 4;  // t - bm
#pragma unroll
      for (int r = 0; r < 4; ++r) {
        const int tloc = tloc0 + r;
        float* trow = dst + hbase + (size_t)(bm + tloc) * D_DIM;
#pragma unroll
        for (int j = 0; j < NJ; ++j) {
          const int d = j * 16 + lrow;
          float val = acc[i][j][r] * outscale;
          if (type < 2) {
            float rotv = ((j < 2) ? -acc[i][j + 2][r] : acc[i][j - 2][r]) *
                         outscale;
            val = val * cs[tloc * D_DIM + d] + rotv * sn[tloc * D_DIM + d];
          }
          trow[d] = val;
        }
      }
    }
  }
}

// ---------------------------------------------------------------------------
// Per-(head,chunk) sums: kv[d][e], ksum[d], vsum[d]. One block per (h,c).
// ---------------------------------------------------------------------------
__global__ __launch_bounds__(256) void chunk_kv(
    const float* __restrict__ k, const float* __restrict__ v,
    float* __restrict__ kvchunk, float* __restrict__ kschunk,
    float* __restrict__ vschunk) {
  __shared__ float Ks[L_CHK][D_DIM];
  __shared__ float Vs[L_CHK][D_DIM];
  int blk = blockIdx.x;  // h*NC + c
  const size_t off = ((size_t)(blk / NC) * T_LEN + (blk % NC) * L_CHK) * D_DIM;
  int tid = threadIdx.x;
#pragma unroll
  for (int m = 0; m < 4; ++m) {
    int el = (tid + m * 256) * 4;
    *(float4*)&((float*)Ks)[el] = *(const float4*)&k[off + el];
    *(float4*)&((float*)Vs)[el] = *(const float4*)&v[off + el];
  }
  __syncthreads();
  int e = tid & 63;
  int q2 = tid >> 6;  // 0..3
  float acc[16] = {};
  for (int t = 0; t < L_CHK; ++t) {
    float ve = Vs[t][e];
#pragma unroll
    for (int m = 0; m < 16; ++m) acc[m] += Ks[t][q2 * 16 + m] * ve;
  }
  float* outb = kvchunk + (size_t)blk * (D_DIM * D_DIM);
#pragma unroll
  for (int m = 0; m < 16; ++m) outb[(q2 * 16 + m) * D_DIM + e] = acc[m];
  if (tid < 64) {
    float s = 0.f;
    for (int t = 0; t < L_CHK; ++t) s += Ks[t][tid];
    kschunk[(size_t)blk * D_DIM + tid] = s;
  } else if (tid < 128) {
    float s = 0.f;
    for (int t = 0; t < L_CHK; ++t) s += Vs[t][tid - 64];
    vschunk[(size_t)blk * D_DIM + (tid - 64)] = s;
  }
}

// ---------------------------------------------------------------------------
// Fused exclusive prefix scans over chunks: blocks 0..255 do the D*D state,
// blocks 256..259 do the ksum/vsum vectors. Fully unrolled loads.
// ---------------------------------------------------------------------------
__global__ __launch_bounds__(256) void scan_fused(
    const float* __restrict__ kvchunk, float* __restrict__ kvpref,
    const float* __restrict__ kschunk, const float* __restrict__ vschunk,
    float* __restrict__ kspref, float* __restrict__ vspref) {
  int b = blockIdx.x;
  int tid = threadIdx.x;
  if (b < 256) {
    int gid = b * 256 + tid;  // h*4096 + de
    int h = gid >> 12;
    int de = gid & 4095;
    float vals[NC];
#pragma unroll
    for (int c = 0; c < NC; ++c)
      vals[c] = kvchunk[((size_t)(h * NC + c) << 12) + de];
    float run = 0.f;
#pragma unroll
    for (int c = 0; c < NC; ++c) {
      kvpref[((size_t)(h * NC + c) << 12) + de] = run;
      run += vals[c];
    }
  } else {
    int gid = (b - 256) * 256 + tid;  // h*64 + d (total 1024)
    int h = gid >> 6, d = gid & 63;
    float kv_[NC], vv_[NC];
#pragma unroll
    for (int c = 0; c < NC; ++c) {
      size_t idx = (size_t)(h * NC + c) * 64 + d;
      kv_[c] = kschunk[idx];
      vv_[c] = vschunk[idx];
    }
    float rk = 0.f, rv = 0.f;
#pragma unroll
    for (int c = 0; c < NC; ++c) {
      size_t idx = (size_t)(h * NC + c) * 64 + d;
      kspref[idx] = rk;
      vspref[idx] = rv;
      rk += kv_[c];
      rv += vv_[c];
    }
  }
}

// ---------------------------------------------------------------------------
// Per-(head,chunk) output -> yh fp16, (T, H*D) layout.
// 256 threads: r = tid&63 (row), g = tid>>6 (16-dim quarter).
// ---------------------------------------------------------------------------
__global__ __launch_bounds__(256) void attn_out(
    const float* __restrict__ q, const float* __restrict__ k,
    const float* __restrict__ v, const float* __restrict__ kvpref,
    const float* __restrict__ kspref, const float* __restrict__ vspref,
    _Float16* __restrict__ yh) {
  __shared__ float Ks[L_CHK * D_DIM];       // phase1: K rows; phase2: KVpref
  __shared__ float Vs[L_CHK * D_DIM];
  __shared__ float Ss[L_CHK][L_CHK + 1];    // stride 65: column access free
  int blk = blockIdx.x;  // h*NC + c
  int h = blk / NC, c = blk % NC;
  int tid = threadIdx.x;
  int r = tid & 63;
  int g = tid >> 6;  // 0..3
  const size_t off = ((size_t)h * T_LEN + c * L_CHK) * D_DIM;
#pragma unroll
  for (int m = 0; m < 4; ++m) {
    int el = (tid + m * 256) * 4;
    *(float4*)&Ks[el] = *(const float4*)&k[off + el];
    *(float4*)&Vs[el] = *(const float4*)&v[off + el];
  }
  float qv[D_DIM];
#pragma unroll
  for (int i = 0; i < 16; ++i) {
    float4 t4 = *(const float4*)&q[off + r * D_DIM + i * 4];
    qv[i * 4 + 0] = t4.x; qv[i * 4 + 1] = t4.y;
    qv[i * 4 + 2] = t4.z; qv[i * 4 + 3] = t4.w;
  }
  __syncthreads();
#pragma unroll
  for (int jj = 0; jj < 16; ++jj) {
    int j = g * 16 + jj;
    const float4* krow = (const float4*)&Ks[j * D_DIM];  // wave-broadcast
    float sdot = 0.f;
#pragma unroll
    for (int i = 0; i < 16; ++i) {
      float4 kj = krow[i];
      sdot += qv[i * 4] * kj.x + qv[i * 4 + 1] * kj.y + qv[i * 4 + 2] * kj.z +
              qv[i * 4 + 3] * kj.w;
    }
    Ss[r][j] = (j <= r) ? (sdot + 1.f) : 0.f;
  }
  __syncthreads();
  const float* kvp = kvpref + (size_t)blk * (D_DIM * D_DIM);
#pragma unroll
  for (int m = 0; m < 4; ++m) {
    int el = (tid + m * 256) * 4;
    *(float4*)&Ks[el] = *(const float4*)&kvp[el];
  }
  __syncthreads();
  const float* ksp = kspref + (size_t)blk * D_DIM;
  const float* vsp = vspref + (size_t)blk * D_DIM;
  float den = (float)(c * L_CHK);  // rowsum(S) supplies the (r+1)
#pragma unroll
  for (int i = 0; i < 16; ++i) {
    float4 kk = *(const float4*)&ksp[i * 4];
    den += qv[i * 4] * kk.x + qv[i * 4 + 1] * kk.y + qv[i * 4 + 2] * kk.z +
           qv[i * 4 + 3] * kk.w;
  }
  float4 num[4];
#pragma unroll
  for (int i = 0; i < 4; ++i) num[i] = *(const float4*)&vsp[g * 16 + i * 4];
#pragma unroll
  for (int d = 0; d < D_DIM; ++d) {
    float qd = qv[d];
    const float4* kvrow = (const float4*)&Ks[d * D_DIM + g * 16];
#pragma unroll
    for (int i = 0; i < 4; ++i) {
      float4 k4 = kvrow[i];
      num[i].x += qd * k4.x; num[i].y += qd * k4.y;
      num[i].z += qd * k4.z; num[i].w += qd * k4.w;
    }
  }
  float rs = 0.f;
#pragma unroll 8
  for (int j = 0; j < L_CHK; ++j) {
    float f = Ss[r][j];
    rs += f;
    const float4* vrow = (const float4*)&Vs[j * D_DIM + g * 16];
#pragma unroll
    for (int i = 0; i < 4; ++i) {
      float4 v4 = vrow[i];
      num[i].x += f * v4.x; num[i].y += f * v4.y;
      num[i].z += f * v4.z; num[i].w += f * v4.w;
    }
  }
  den += rs;
  float inv = 1.f / den;
  int t = c * L_CHK + r;
  size_t ybase = (size_t)t * (H_NUM * D_DIM) + h * D_DIM + g * 16;
#pragma unroll
  for (int i = 0; i < 4; ++i) {
    h4 hv;
    hv[0] = (_Float16)(num[i].x * inv);
    hv[1] = (_Float16)(num[i].y * inv);
    hv[2] = (_Float16)(num[i].z * inv);
    hv[3] = (_Float16)(num[i].w * inv);
    *(h4*)&yh[ybase + i * 4] = hv;
  }
}

// ---------------------------------------------------------------------------
extern "C" void kernel_launch(void* const* d_in, const int* in_sizes, int n_in,
                              void* d_out, int out_size, void* d_ws,
                              size_t ws_size, hipStream_t stream) {
  const float* x = (const float*)d_in[0];       // (1,2048,1024)
  const float* w_attn = (const float*)d_in[1];  // (3072,1024)
  const float* w_proj = (const float*)d_in[2];  // (1024,1024)
  const float* cosb = (const float*)d_in[3];    // (2048,64)
  const float* sinb = (const float*)d_in[4];    // (2048,64)
  float* out = (float*)d_out;                   // (2048,1024)

  char* ws = (char*)d_ws;
  // Region A (0..16MB): kvchunk, kvpref
  float* kvchunk = (float*)ws;                       // 8 MB
  float* kvpref = (float*)(ws + 8388608);            // 8 MB
  // Region B (24..48MB): q/k/v fp32
  float* qbuf = (float*)(ws + 25165824);
  float* kbuf = (float*)(ws + 25165824 + 8388608);
  float* vbuf = (float*)(ws + 25165824 + 16777216);
  // Region C (48..56MB): xh/xl (live split->QKV GEMM); then yh.
  _Float16* xh = (_Float16*)(ws + 50331648);
  _Float16* xl = (_Float16*)(ws + 50331648 + 4194304);
  _Float16* yh = (_Float16*)(ws + 50331648);
  // Region D (56..68MB): wah/wal (live split->QKV GEMM); then scan vectors.
  _Float16* wah = (_Float16*)(ws + 58720256);
  _Float16* wal = (_Float16*)(ws + 58720256 + 6291456);
  float* kschunk = (float*)(ws + 58720256);
  float* vschunk = (float*)(ws + 58720256 + 131072);
  float* kspref = (float*)(ws + 58720256 + 262144);
  float* vspref = (float*)(ws + 58720256 + 393216);
  // Region E (68..72MB): wph (live whole call).
  _Float16* wph = (_Float16*)(ws + 71303168);

  // 0) fused splits (scale 64, undone in epilogues); w_proj hi-only
  split3_f16<<<3072, 256, 0, stream>>>(x, xh, xl, w_attn, wah, wal, w_proj,
                                       wph);

  // 1) qkv GEMM (f16x3) + fused RoPE/split -> q,k,v [H][T][D] fp32; 2^-12
  {
    dim3 grid(QKV_N / 128, T_LEN / 64);   // 24 x 32 = 768 blocks
    gemm_nt_f16<128, true, true><<<grid, 256, 0, stream>>>(
        xh, xl, wah, wal, nullptr, cosb, sinb, qbuf, kbuf, vbuf, T_LEN, QKV_N,
        C_DIM, 1.f / 4096.f);
  }
  // 2) per-chunk sums
  chunk_kv<<<H_NUM * NC, 256, 0, stream>>>(kbuf, vbuf, kvchunk, kschunk,
                                           vschunk);
  // 3) fused prefix scans (256 blocks kv + 4 blocks vec)
  scan_fused<<<260, 256, 0, stream>>>(kvchunk, kvpref, kschunk, vschunk,
                                      kspref, vspref);
  // 4) attention output -> yh (T, H*D) fp16
  attn_out<<<H_NUM * NC, 256, 0, stream>>>(qbuf, kbuf, vbuf, kvpref, kspref,
                                           vspref, yh);
  // 5) out = y @ w_proj^T (plain fp16, 1 MFMA): M=2048, N=1024, K=1024; 2^-6
  {
    dim3 grid(C_DIM / 64, T_LEN / 64);    // 16 x 32 = 512 blocks
    gemm_nt_f16<64, false, false><<<grid, 256, 0, stream>>>(
        yh, nullptr, wph, nullptr, out, nullptr, nullptr, nullptr, nullptr,
        nullptr, T_LEN, C_DIM, C_DIM, 1.f / 64.f);
  }
}

// Round 8
// 181.011 us; speedup vs baseline: 3.0337x; 1.0317x over previous
//
#include <hip/hip_runtime.h>

// Problem constants (B=1)
#define T_LEN 2048
#define C_DIM 1024
#define H_NUM 16
#define D_DIM 64
#define QKV_N (3 * H_NUM * D_DIM)   // 3072
#define L_CHK 64
#define NC (T_LEN / L_CHK)          // 32

typedef _Float16 h8 __attribute__((ext_vector_type(8)));
typedef _Float16 h4 __attribute__((ext_vector_type(4)));
typedef float f32x4 __attribute__((ext_vector_type(4)));

// ---------------------------------------------------------------------------
// Fused fp32 -> fp16 split, scale 64. x & w_attn get hi+lo; w_proj hi only.
// ---------------------------------------------------------------------------
__global__ __launch_bounds__(256) void split3_f16(
    const float* __restrict__ x, _Float16* __restrict__ xh,
    _Float16* __restrict__ xl, const float* __restrict__ wa,
    _Float16* __restrict__ wah, _Float16* __restrict__ wal,
    const float* __restrict__ wp, _Float16* __restrict__ wph) {
  int i = (blockIdx.x * 256 + threadIdx.x) * 8;
  const float* src;
  _Float16 *dh, *dl = nullptr;
  int base;
  if (i < 2097152) {
    src = x; dh = xh; dl = xl; base = i;
  } else if (i < 2097152 + 3145728) {
    src = wa; dh = wah; dl = wal; base = i - 2097152;
  } else {
    src = wp; dh = wph; base = i - 5242880;
  }
  float4 a = *(const float4*)(src + base);
  float4 b = *(const float4*)(src + base + 4);
  float v[8] = {a.x, a.y, a.z, a.w, b.x, b.y, b.z, b.w};
  h8 hv, lv;
#pragma unroll
  for (int j = 0; j < 8; ++j) {
    float s = v[j] * 64.f;
    _Float16 h = (_Float16)s;
    hv[j] = h;
    lv[j] = (_Float16)(s - (float)h);
  }
  *(h8*)(dh + base) = hv;
  if (dl) *(h8*)(dl + base) = lv;
}

// ---------------------------------------------------------------------------
// fp16 NT MFMA GEMM, BK=64 (16 K-steps @ K=1024 -> half the barrier drains
// of BK=32; LDS 48 KB SPLIT3 -> still 3 blocks/CU).
// SPLIT3: acc += Ah*Bh + Ah*Bl + Al*Bh (fp32-grade). !SPLIT3: 1 MFMA.
// Tile BM=64 x BN, 256 thr = 2x2 waves of 32 x BN/2.
// Staging: global_load_lds w=16; chunk = 8 rows x 64 halves = 1 KB,
// lane -> row ch*8+(lane>>3), col (lane&7)*8 (LDS dst = base + lane*16).
// ROPE epilogue (BN=128): wave's 64-col span == one q/k/v 64-dim block of
// one head; rotate d<->d+-32 == acc[i][j]<->acc[i][j+-2] (lane-local).
// ---------------------------------------------------------------------------
template <int BN, bool ROPE, bool SPLIT3>
__global__ __launch_bounds__(256) void gemm_nt_f16(
    const _Float16* __restrict__ Ah, const _Float16* __restrict__ Al,
    const _Float16* __restrict__ Bh, const _Float16* __restrict__ Bl,
    float* __restrict__ C, const float* __restrict__ cosb,
    const float* __restrict__ sinb, float* __restrict__ qout,
    float* __restrict__ kout, float* __restrict__ vout, int M, int N, int K,
    float outscale) {
  constexpr int NJ = BN / 32;  // N-tiles per wave
  constexpr int NARR = SPLIT3 ? 2 : 1;
  constexpr int GEMM_BYTES = (64 * 64 * 2 + BN * 64 * 2) * NARR;
  constexpr int ROPE_BYTES = ROPE ? (2 * 64 * 64 * 4) : 0;
  constexpr int SMEM_BYTES = GEMM_BYTES > ROPE_BYTES ? GEMM_BYTES : ROPE_BYTES;
  __shared__ __align__(16) char smem[SMEM_BYTES];
  _Float16* sAh = (_Float16*)smem;
  _Float16* sAl = sAh + 64 * 64;                       // SPLIT3 only
  _Float16* sBh = sAh + 64 * 64 * NARR;
  _Float16* sBl = sBh + BN * 64;                       // SPLIT3 only
  const int tid = threadIdx.x;
  const int wave = tid >> 6;
  const int lane = tid & 63;
  const int bm = blockIdx.y * 64;
  const int bn = blockIdx.x * BN;
  const int wm = wave >> 1;          // 0..1 -> 32-row half
  const int wn = wave & 1;           // 0..1 -> BN/2-col half
  const int srow = lane >> 3;        // 0..7 staging row within chunk
  const int scol = (lane & 7) * 8;   // staging col (halves)
  const int quad = lane >> 4;        // 0..3
  const int lrow = lane & 15;

  f32x4 acc[2][NJ];
#pragma unroll
  for (int i = 0; i < 2; ++i)
#pragma unroll
    for (int j = 0; j < NJ; ++j) acc[i][j] = (f32x4){0.f, 0.f, 0.f, 0.f};

  for (int k0 = 0; k0 < K; k0 += 64) {
    // stage A: 8 chunks of 8 rows x 64 halves; 2 per wave per array
#pragma unroll
    for (int it = 0; it < 2; ++it) {
      const int ch = wave + it * 4;  // 0..7
      const int row = ch * 8 + srow;
      const _Float16* ga = Ah + (size_t)(bm + row) * K + k0 + scol;
      __builtin_amdgcn_global_load_lds(
          (const __attribute__((address_space(1))) void*)ga,
          (__attribute__((address_space(3))) void*)(sAh + ch * 512), 16, 0, 0);
      if constexpr (SPLIT3) {
        const _Float16* gb = Al + (size_t)(bm + row) * K + k0 + scol;
        __builtin_amdgcn_global_load_lds(
            (const __attribute__((address_space(1))) void*)gb,
            (__attribute__((address_space(3))) void*)(sAl + ch * 512), 16, 0,
            0);
      }
    }
    // stage B: BN/8 chunks; BN/32 per wave per array
#pragma unroll
    for (int it = 0; it < BN / 32; ++it) {
      const int ch = wave + it * 4;  // 0..BN/8-1
      const int row = ch * 8 + srow;
      const _Float16* ga = Bh + (size_t)(bn + row) * K + k0 + scol;
      __builtin_amdgcn_global_load_lds(
          (const __attribute__((address_space(1))) void*)ga,
          (__attribute__((address_space(3))) void*)(sBh + ch * 512), 16, 0, 0);
      if constexpr (SPLIT3) {
        const _Float16* gb = Bl + (size_t)(bn + row) * K + k0 + scol;
        __builtin_amdgcn_global_load_lds(
            (const __attribute__((address_space(1))) void*)gb,
            (__attribute__((address_space(3))) void*)(sBl + ch * 512), 16, 0,
            0);
      }
    }
    __syncthreads();
#pragma unroll
    for (int kk = 0; kk < 2; ++kk) {
      h8 ah[2], al[2], bh[NJ], bl[NJ];
#pragma unroll
      for (int i = 0; i < 2; ++i) {
        const int ra = (wm * 32 + i * 16 + lrow) * 64 + kk * 32 + quad * 8;
        ah[i] = *(const h8*)&sAh[ra];
        if constexpr (SPLIT3) al[i] = *(const h8*)&sAl[ra];
      }
#pragma unroll
      for (int j = 0; j < NJ; ++j) {
        const int rb =
            (wn * (BN / 2) + j * 16 + lrow) * 64 + kk * 32 + quad * 8;
        bh[j] = *(const h8*)&sBh[rb];
        if constexpr (SPLIT3) bl[j] = *(const h8*)&sBl[rb];
      }
#pragma unroll
      for (int i = 0; i < 2; ++i)
#pragma unroll
        for (int j = 0; j < NJ; ++j) {
          acc[i][j] = __builtin_amdgcn_mfma_f32_16x16x32_f16(
              ah[i], bh[j], acc[i][j], 0, 0, 0);
          if constexpr (SPLIT3) {
            acc[i][j] = __builtin_amdgcn_mfma_f32_16x16x32_f16(
                ah[i], bl[j], acc[i][j], 0, 0, 0);
            acc[i][j] = __builtin_amdgcn_mfma_f32_16x16x32_f16(
                al[i], bh[j], acc[i][j], 0, 0, 0);
          }
        }
    }
    __syncthreads();
  }
  // epilogue: C/D layout col=lane&15, row=quad*4+reg
  if constexpr (!ROPE) {
#pragma unroll
    for (int i = 0; i < 2; ++i) {
      const int rbase = bm + wm * 32 + i * 16 + quad * 4;
#pragma unroll
      for (int j = 0; j < NJ; ++j) {
        const int col = bn + wn * (BN / 2) + j * 16 + lrow;
#pragma unroll
        for (int r = 0; r < 4; ++r)
          C[(size_t)(rbase + r) * N + col] = acc[i][j][r] * outscale;
      }
    }
  } else {
    float* cs = (float*)smem;
    float* sn = cs + 4096;
#pragma unroll
    for (int m = 0; m < 4; ++m) {
      int el = (tid + m * 256) * 4;
      *(float4*)&cs[el] = *(const float4*)&cosb[bm * D_DIM + el];
      *(float4*)&sn[el] = *(const float4*)&sinb[bm * D_DIM + el];
    }
    __syncthreads();
    const int colbase = bn + wn * 64;       // multiple of 64
    const int type = (colbase >> 6) % 3;    // 0=q, 1=k, 2=v
    const int head = colbase / 192;
    float* dst = (type == 0) ? qout : (type == 1) ? kout : vout;
    const size_t hbase = (size_t)head * T_LEN * D_DIM;
#pragma unroll
    for (int i = 0; i < 2; ++i) {
      const int tloc0 = wm * 32 + i * 16 + quad * 4;  // t - bm
#pragma unroll
      for (int r = 0; r < 4; ++r) {
        const int tloc = tloc0 + r;
        float* trow = dst + hbase + (size_t)(bm + tloc) * D_DIM;
#pragma unroll
        for (int j = 0; j < NJ; ++j) {
          const int d = j * 16 + lrow;
          float val = acc[i][j][r] * outscale;
          if (type < 2) {
            float rotv = ((j < 2) ? -acc[i][j + 2][r] : acc[i][j - 2][r]) *
                         outscale;
            val = val * cs[tloc * D_DIM + d] + rotv * sn[tloc * D_DIM + d];
          }
          trow[d] = val;
        }
      }
    }
  }
}

// ---------------------------------------------------------------------------
// Per-(head,chunk) sums: kv[d][e], ksum[d], vsum[d]. One block per (h,c).
// ---------------------------------------------------------------------------
__global__ __launch_bounds__(256) void chunk_kv(
    const float* __restrict__ k, const float* __restrict__ v,
    float* __restrict__ kvchunk, float* __restrict__ kschunk,
    float* __restrict__ vschunk) {
  __shared__ float Ks[L_CHK][D_DIM];
  __shared__ float Vs[L_CHK][D_DIM];
  int blk = blockIdx.x;  // h*NC + c
  const size_t off = ((size_t)(blk / NC) * T_LEN + (blk % NC) * L_CHK) * D_DIM;
  int tid = threadIdx.x;
#pragma unroll
  for (int m = 0; m < 4; ++m) {
    int el = (tid + m * 256) * 4;
    *(float4*)&((float*)Ks)[el] = *(const float4*)&k[off + el];
    *(float4*)&((float*)Vs)[el] = *(const float4*)&v[off + el];
  }
  __syncthreads();
  int e = tid & 63;
  int q2 = tid >> 6;  // 0..3
  float acc[16] = {};
  for (int t = 0; t < L_CHK; ++t) {
    float ve = Vs[t][e];
#pragma unroll
    for (int m = 0; m < 16; ++m) acc[m] += Ks[t][q2 * 16 + m] * ve;
  }
  float* outb = kvchunk + (size_t)blk * (D_DIM * D_DIM);
#pragma unroll
  for (int m = 0; m < 16; ++m) outb[(q2 * 16 + m) * D_DIM + e] = acc[m];
  if (tid < 64) {
    float s = 0.f;
    for (int t = 0; t < L_CHK; ++t) s += Ks[t][tid];
    kschunk[(size_t)blk * D_DIM + tid] = s;
  } else if (tid < 128) {
    float s = 0.f;
    for (int t = 0; t < L_CHK; ++t) s += Vs[t][tid - 64];
    vschunk[(size_t)blk * D_DIM + (tid - 64)] = s;
  }
}

// ---------------------------------------------------------------------------
// Fused exclusive prefix scans over chunks: blocks 0..255 do the D*D state,
// blocks 256..259 do the ksum/vsum vectors. Fully unrolled loads.
// ---------------------------------------------------------------------------
__global__ __launch_bounds__(256) void scan_fused(
    const float* __restrict__ kvchunk, float* __restrict__ kvpref,
    const float* __restrict__ kschunk, const float* __restrict__ vschunk,
    float* __restrict__ kspref, float* __restrict__ vspref) {
  int b = blockIdx.x;
  int tid = threadIdx.x;
  if (b < 256) {
    int gid = b * 256 + tid;  // h*4096 + de
    int h = gid >> 12;
    int de = gid & 4095;
    float vals[NC];
#pragma unroll
    for (int c = 0; c < NC; ++c)
      vals[c] = kvchunk[((size_t)(h * NC + c) << 12) + de];
    float run = 0.f;
#pragma unroll
    for (int c = 0; c < NC; ++c) {
      kvpref[((size_t)(h * NC + c) << 12) + de] = run;
      run += vals[c];
    }
  } else {
    int gid = (b - 256) * 256 + tid;  // h*64 + d (total 1024)
    int h = gid >> 6, d = gid & 63;
    float kv_[NC], vv_[NC];
#pragma unroll
    for (int c = 0; c < NC; ++c) {
      size_t idx = (size_t)(h * NC + c) * 64 + d;
      kv_[c] = kschunk[idx];
      vv_[c] = vschunk[idx];
    }
    float rk = 0.f, rv = 0.f;
#pragma unroll
    for (int c = 0; c < NC; ++c) {
      size_t idx = (size_t)(h * NC + c) * 64 + d;
      kspref[idx] = rk;
      vspref[idx] = rv;
      rk += kv_[c];
      rv += vv_[c];
    }
  }
}

// ---------------------------------------------------------------------------
// Per-(head,chunk) output -> yh fp16, (T, H*D) layout.
// 256 threads: r = tid&63 (row), g = tid>>6 (16-dim quarter).
// ---------------------------------------------------------------------------
__global__ __launch_bounds__(256) void attn_out(
    const float* __restrict__ q, const float* __restrict__ k,
    const float* __restrict__ v, const float* __restrict__ kvpref,
    const float* __restrict__ kspref, const float* __restrict__ vspref,
    _Float16* __restrict__ yh) {
  __shared__ float Ks[L_CHK * D_DIM];       // phase1: K rows; phase2: KVpref
  __shared__ float Vs[L_CHK * D_DIM];
  __shared__ float Ss[L_CHK][L_CHK + 1];    // stride 65: column access free
  int blk = blockIdx.x;  // h*NC + c
  int h = blk / NC, c = blk % NC;
  int tid = threadIdx.x;
  int r = tid & 63;
  int g = tid >> 6;  // 0..3
  const size_t off = ((size_t)h * T_LEN + c * L_CHK) * D_DIM;
#pragma unroll
  for (int m = 0; m < 4; ++m) {
    int el = (tid + m * 256) * 4;
    *(float4*)&Ks[el] = *(const float4*)&k[off + el];
    *(float4*)&Vs[el] = *(const float4*)&v[off + el];
  }
  float qv[D_DIM];
#pragma unroll
  for (int i = 0; i < 16; ++i) {
    float4 t4 = *(const float4*)&q[off + r * D_DIM + i * 4];
    qv[i * 4 + 0] = t4.x; qv[i * 4 + 1] = t4.y;
    qv[i * 4 + 2] = t4.z; qv[i * 4 + 3] = t4.w;
  }
  __syncthreads();
#pragma unroll
  for (int jj = 0; jj < 16; ++jj) {
    int j = g * 16 + jj;
    const float4* krow = (const float4*)&Ks[j * D_DIM];  // wave-broadcast
    float sdot = 0.f;
#pragma unroll
    for (int i = 0; i < 16; ++i) {
      float4 kj = krow[i];
      sdot += qv[i * 4] * kj.x + qv[i * 4 + 1] * kj.y + qv[i * 4 + 2] * kj.z +
              qv[i * 4 + 3] * kj.w;
    }
    Ss[r][j] = (j <= r) ? (sdot + 1.f) : 0.f;
  }
  __syncthreads();
  const float* kvp = kvpref + (size_t)blk * (D_DIM * D_DIM);
#pragma unroll
  for (int m = 0; m < 4; ++m) {
    int el = (tid + m * 256) * 4;
    *(float4*)&Ks[el] = *(const float4*)&kvp[el];
  }
  __syncthreads();
  const float* ksp = kspref + (size_t)blk * D_DIM;
  const float* vsp = vspref + (size_t)blk * D_DIM;
  float den = (float)(c * L_CHK);  // rowsum(S) supplies the (r+1)
#pragma unroll
  for (int i = 0; i < 16; ++i) {
    float4 kk = *(const float4*)&ksp[i * 4];
    den += qv[i * 4] * kk.x + qv[i * 4 + 1] * kk.y + qv[i * 4 + 2] * kk.z +
           qv[i * 4 + 3] * kk.w;
  }
  float4 num[4];
#pragma unroll
  for (int i = 0; i < 4; ++i) num[i] = *(const float4*)&vsp[g * 16 + i * 4];
#pragma unroll
  for (int d = 0; d < D_DIM; ++d) {
    float qd = qv[d];
    const float4* kvrow = (const float4*)&Ks[d * D_DIM + g * 16];
#pragma unroll
    for (int i = 0; i < 4; ++i) {
      float4 k4 = kvrow[i];
      num[i].x += qd * k4.x; num[i].y += qd * k4.y;
      num[i].z += qd * k4.z; num[i].w += qd * k4.w;
    }
  }
  float rs = 0.f;
#pragma unroll 8
  for (int j = 0; j < L_CHK; ++j) {
    float f = Ss[r][j];
    rs += f;
    const float4* vrow = (const float4*)&Vs[j * D_DIM + g * 16];
#pragma unroll
    for (int i = 0; i < 4; ++i) {
      float4 v4 = vrow[i];
      num[i].x += f * v4.x; num[i].y += f * v4.y;
      num[i].z += f * v4.z; num[i].w += f * v4.w;
    }
  }
  den += rs;
  float inv = 1.f / den;
  int t = c * L_CHK + r;
  size_t ybase = (size_t)t * (H_NUM * D_DIM) + h * D_DIM + g * 16;
#pragma unroll
  for (int i = 0; i < 4; ++i) {
    h4 hv;
    hv[0] = (_Float16)(num[i].x * inv);
    hv[1] = (_Float16)(num[i].y * inv);
    hv[2] = (_Float16)(num[i].z * inv);
    hv[3] = (_Float16)(num[i].w * inv);
    *(h4*)&yh[ybase + i * 4] = hv;
  }
}

// ---------------------------------------------------------------------------
extern "C" void kernel_launch(void* const* d_in, const int* in_sizes, int n_in,
                              void* d_out, int out_size, void* d_ws,
                              size_t ws_size, hipStream_t stream) {
  const float* x = (const float*)d_in[0];       // (1,2048,1024)
  const float* w_attn = (const float*)d_in[1];  // (3072,1024)
  const float* w_proj = (const float*)d_in[2];  // (1024,1024)
  const float* cosb = (const float*)d_in[3];    // (2048,64)
  const float* sinb = (const float*)d_in[4];    // (2048,64)
  float* out = (float*)d_out;                   // (2048,1024)

  char* ws = (char*)d_ws;
  // Region A (0..16MB): kvchunk, kvpref
  float* kvchunk = (float*)ws;                       // 8 MB
  float* kvpref = (float*)(ws + 8388608);            // 8 MB
  // Region B (24..48MB): q/k/v fp32
  float* qbuf = (float*)(ws + 25165824);
  float* kbuf = (float*)(ws + 25165824 + 8388608);
  float* vbuf = (float*)(ws + 25165824 + 16777216);
  // Region C (48..56MB): xh/xl (live split->QKV GEMM); then yh.
  _Float16* xh = (_Float16*)(ws + 50331648);
  _Float16* xl = (_Float16*)(ws + 50331648 + 4194304);
  _Float16* yh = (_Float16*)(ws + 50331648);
  // Region D (56..68MB): wah/wal (live split->QKV GEMM); then scan vectors.
  _Float16* wah = (_Float16*)(ws + 58720256);
  _Float16* wal = (_Float16*)(ws + 58720256 + 6291456);
  float* kschunk = (float*)(ws + 58720256);
  float* vschunk = (float*)(ws + 58720256 + 131072);
  float* kspref = (float*)(ws + 58720256 + 262144);
  float* vspref = (float*)(ws + 58720256 + 393216);
  // Region E (68..72MB): wph (live whole call).
  _Float16* wph = (_Float16*)(ws + 71303168);

  // 0) fused splits (scale 64, undone in epilogues); w_proj hi-only
  split3_f16<<<3072, 256, 0, stream>>>(x, xh, xl, w_attn, wah, wal, w_proj,
                                       wph);

  // 1) qkv GEMM (f16x3, BK=64) + fused RoPE/split -> q,k,v [H][T][D]; 2^-12
  {
    dim3 grid(QKV_N / 128, T_LEN / 64);   // 24 x 32 = 768 blocks
    gemm_nt_f16<128, true, true><<<grid, 256, 0, stream>>>(
        xh, xl, wah, wal, nullptr, cosb, sinb, qbuf, kbuf, vbuf, T_LEN, QKV_N,
        C_DIM, 1.f / 4096.f);
  }
  // 2) per-chunk sums
  chunk_kv<<<H_NUM * NC, 256, 0, stream>>>(kbuf, vbuf, kvchunk, kschunk,
                                           vschunk);
  // 3) fused prefix scans (256 blocks kv + 4 blocks vec)
  scan_fused<<<260, 256, 0, stream>>>(kvchunk, kvpref, kschunk, vschunk,
                                      kspref, vspref);
  // 4) attention output -> yh (T, H*D) fp16
  attn_out<<<H_NUM * NC, 256, 0, stream>>>(qbuf, kbuf, vbuf, kvpref, kspref,
                                           vspref, yh);
  // 5) out = y @ w_proj^T (plain fp16, BK=64): M=2048, N=1024, K=1024; 2^-6
  {
    dim3 grid(C_DIM / 64, T_LEN / 64);    // 16 x 32 = 512 blocks
    gemm_nt_f16<64, false, false><<<grid, 256, 0, stream>>>(
        yh, nullptr, wph, nullptr, out, nullptr, nullptr, nullptr, nullptr,
        nullptr, T_LEN, C_DIM, C_DIM, 1.f / 64.f);
  }
}

// Round 9
// 172.213 us; speedup vs baseline: 3.1887x; 1.0511x over previous
//
#include <hip/hip_runtime.h>

// Problem constants (B=1)
#define T_LEN 2048
#define C_DIM 1024
#define H_NUM 16
#define D_DIM 64
#define QKV_N (3 * H_NUM * D_DIM)   // 3072
#define L_CHK 64
#define NC (T_LEN / L_CHK)          // 32

typedef _Float16 h8 __attribute__((ext_vector_type(8)));
typedef _Float16 h4 __attribute__((ext_vector_type(4)));
typedef float f32x4 __attribute__((ext_vector_type(4)));

// ---------------------------------------------------------------------------
// Fused fp32 -> fp16 split, scale 64. x & w_attn get hi+lo; w_proj hi only.
// ---------------------------------------------------------------------------
__global__ __launch_bounds__(256) void split3_f16(
    const float* __restrict__ x, _Float16* __restrict__ xh,
    _Float16* __restrict__ xl, const float* __restrict__ wa,
    _Float16* __restrict__ wah, _Float16* __restrict__ wal,
    const float* __restrict__ wp, _Float16* __restrict__ wph) {
  int i = (blockIdx.x * 256 + threadIdx.x) * 8;
  const float* src;
  _Float16 *dh, *dl = nullptr;
  int base;
  if (i < 2097152) {
    src = x; dh = xh; dl = xl; base = i;
  } else if (i < 2097152 + 3145728) {
    src = wa; dh = wah; dl = wal; base = i - 2097152;
  } else {
    src = wp; dh = wph; base = i - 5242880;
  }
  float4 a = *(const float4*)(src + base);
  float4 b = *(const float4*)(src + base + 4);
  float v[8] = {a.x, a.y, a.z, a.w, b.x, b.y, b.z, b.w};
  h8 hv, lv;
#pragma unroll
  for (int j = 0; j < 8; ++j) {
    float s = v[j] * 64.f;
    _Float16 h = (_Float16)s;
    hv[j] = h;
    lv[j] = (_Float16)(s - (float)h);
  }
  *(h8*)(dh + base) = hv;
  if (dl) *(h8*)(dl + base) = lv;
}

// ---------------------------------------------------------------------------
// fp16 NT MFMA GEMM, BK=64, XOR-swizzled LDS (16B-block granularity).
// LDS slot (row, b) holds global block (b ^ (row&7)); 128B rows would
// otherwise all start at bank 0 (16-way conflict). After swizzle a
// quad-group's 16 rows hit 8 distinct bank-groups -> 2 lanes/bank = free.
// SPLIT3: acc += Ah*Bh + Ah*Bl + Al*Bh (fp32-grade). !SPLIT3: 1 MFMA.
// Tile BM=64 x BN, 256 thr = 2x2 waves of 32 x BN/2.
// ROPE epilogue (BN=128): wave's 64-col span == one q/k/v 64-dim block of
// one head; rotate d<->d+-32 == acc[i][j]<->acc[i][j+-2] (lane-local).
// ---------------------------------------------------------------------------
template <int BN, bool ROPE, bool SPLIT3>
__global__ __launch_bounds__(256) void gemm_nt_f16(
    const _Float16* __restrict__ Ah, const _Float16* __restrict__ Al,
    const _Float16* __restrict__ Bh, const _Float16* __restrict__ Bl,
    float* __restrict__ C, const float* __restrict__ cosb,
    const float* __restrict__ sinb, float* __restrict__ qout,
    float* __restrict__ kout, float* __restrict__ vout, int M, int N, int K,
    float outscale) {
  constexpr int NJ = BN / 32;  // N-tiles per wave
  constexpr int NARR = SPLIT3 ? 2 : 1;
  constexpr int GEMM_BYTES = (64 * 64 * 2 + BN * 64 * 2) * NARR;
  constexpr int ROPE_BYTES = ROPE ? (2 * 64 * 64 * 4) : 0;
  constexpr int SMEM_BYTES = GEMM_BYTES > ROPE_BYTES ? GEMM_BYTES : ROPE_BYTES;
  __shared__ __align__(16) char smem[SMEM_BYTES];
  _Float16* sAh = (_Float16*)smem;
  _Float16* sAl = sAh + 64 * 64;                       // SPLIT3 only
  _Float16* sBh = sAh + 64 * 64 * NARR;
  _Float16* sBl = sBh + BN * 64;                       // SPLIT3 only
  const int tid = threadIdx.x;
  const int wave = tid >> 6;
  const int lane = tid & 63;
  const int bm = blockIdx.y * 64;
  const int bn = blockIdx.x * BN;
  const int wm = wave >> 1;          // 0..1 -> 32-row half
  const int wn = wave & 1;           // 0..1 -> BN/2-col half
  const int srow = lane >> 3;        // 0..7 staging row within chunk
  // swizzled global column block for this lane's fixed LDS slot:
  const int sblk = ((lane & 7) ^ srow) * 8;  // halves offset
  const int quad = lane >> 4;        // 0..3
  const int lrow = lane & 15;

  f32x4 acc[2][NJ];
#pragma unroll
  for (int i = 0; i < 2; ++i)
#pragma unroll
    for (int j = 0; j < NJ; ++j) acc[i][j] = (f32x4){0.f, 0.f, 0.f, 0.f};

  for (int k0 = 0; k0 < K; k0 += 64) {
    // stage A: 8 chunks of 8 rows x 64 halves; 2 per wave per array
#pragma unroll
    for (int it = 0; it < 2; ++it) {
      const int ch = wave + it * 4;  // 0..7
      const int row = ch * 8 + srow;
      const _Float16* ga = Ah + (size_t)(bm + row) * K + k0 + sblk;
      __builtin_amdgcn_global_load_lds(
          (const __attribute__((address_space(1))) void*)ga,
          (__attribute__((address_space(3))) void*)(sAh + ch * 512), 16, 0, 0);
      if constexpr (SPLIT3) {
        const _Float16* gb = Al + (size_t)(bm + row) * K + k0 + sblk;
        __builtin_amdgcn_global_load_lds(
            (const __attribute__((address_space(1))) void*)gb,
            (__attribute__((address_space(3))) void*)(sAl + ch * 512), 16, 0,
            0);
      }
    }
    // stage B: BN/8 chunks; BN/32 per wave per array
#pragma unroll
    for (int it = 0; it < BN / 32; ++it) {
      const int ch = wave + it * 4;  // 0..BN/8-1
      const int row = ch * 8 + srow;
      const _Float16* ga = Bh + (size_t)(bn + row) * K + k0 + sblk;
      __builtin_amdgcn_global_load_lds(
          (const __attribute__((address_space(1))) void*)ga,
          (__attribute__((address_space(3))) void*)(sBh + ch * 512), 16, 0, 0);
      if constexpr (SPLIT3) {
        const _Float16* gb = Bl + (size_t)(bn + row) * K + k0 + sblk;
        __builtin_amdgcn_global_load_lds(
            (const __attribute__((address_space(1))) void*)gb,
            (__attribute__((address_space(3))) void*)(sBl + ch * 512), 16, 0,
            0);
      }
    }
    __syncthreads();
#pragma unroll
    for (int kk = 0; kk < 2; ++kk) {
      h8 ah[2], al[2], bh[NJ], bl[NJ];
#pragma unroll
      for (int i = 0; i < 2; ++i) {
        const int row = wm * 32 + i * 16 + lrow;
        const int ra = row * 64 + (((kk * 4 + quad) ^ (row & 7)) * 8);
        ah[i] = *(const h8*)&sAh[ra];
        if constexpr (SPLIT3) al[i] = *(const h8*)&sAl[ra];
      }
#pragma unroll
      for (int j = 0; j < NJ; ++j) {
        const int row = wn * (BN / 2) + j * 16 + lrow;
        const int rb = row * 64 + (((kk * 4 + quad) ^ (row & 7)) * 8);
        bh[j] = *(const h8*)&sBh[rb];
        if constexpr (SPLIT3) bl[j] = *(const h8*)&sBl[rb];
      }
#pragma unroll
      for (int i = 0; i < 2; ++i)
#pragma unroll
        for (int j = 0; j < NJ; ++j) {
          acc[i][j] = __builtin_amdgcn_mfma_f32_16x16x32_f16(
              ah[i], bh[j], acc[i][j], 0, 0, 0);
          if constexpr (SPLIT3) {
            acc[i][j] = __builtin_amdgcn_mfma_f32_16x16x32_f16(
                ah[i], bl[j], acc[i][j], 0, 0, 0);
            acc[i][j] = __builtin_amdgcn_mfma_f32_16x16x32_f16(
                al[i], bh[j], acc[i][j], 0, 0, 0);
          }
        }
    }
    __syncthreads();
  }
  // epilogue: C/D layout col=lane&15, row=quad*4+reg
  if constexpr (!ROPE) {
#pragma unroll
    for (int i = 0; i < 2; ++i) {
      const int rbase = bm + wm * 32 + i * 16 + quad * 4;
#pragma unroll
      for (int j = 0; j < NJ; ++j) {
        const int col = bn + wn * (BN / 2) + j * 16 + lrow;
#pragma unroll
        for (int r = 0; r < 4; ++r)
          C[(size_t)(rbase + r) * N + col] = acc[i][j][r] * outscale;
      }
    }
  } else {
    float* cs = (float*)smem;
    float* sn = cs + 4096;
#pragma unroll
    for (int m = 0; m < 4; ++m) {
      int el = (tid + m * 256) * 4;
      *(float4*)&cs[el] = *(const float4*)&cosb[bm * D_DIM + el];
      *(float4*)&sn[el] = *(const float4*)&sinb[bm * D_DIM + el];
    }
    __syncthreads();
    const int colbase = bn + wn * 64;       // multiple of 64
    const int type = (colbase >> 6) % 3;    // 0=q, 1=k, 2=v
    const int head = colbase / 192;
    float* dst = (type == 0) ? qout : (type == 1) ? kout : vout;
    const size_t hbase = (size_t)head * T_LEN * D_DIM;
#pragma unroll
    for (int i = 0; i < 2; ++i) {
      const int tloc0 = wm * 32 + i * 16 + quad * 4;  // t - bm
#pragma unroll
      for (int r = 0; r < 4; ++r) {
        const int tloc = tloc0 + r;
        float* trow = dst + hbase + (size_t)(bm + tloc) * D_DIM;
#pragma unroll
        for (int j = 0; j < NJ; ++j) {
          const int d = j * 16 + lrow;
          float val = acc[i][j][r] * outscale;
          if (type < 2) {
            float rotv = ((j < 2) ? -acc[i][j + 2][r] : acc[i][j - 2][r]) *
                         outscale;
            val = val * cs[tloc * D_DIM + d] + rotv * sn[tloc * D_DIM + d];
          }
          trow[d] = val;
        }
      }
    }
  }
}

// ---------------------------------------------------------------------------
// Per-(head,chunk) sums: kv[d][e], ksum[d], vsum[d]. One block per (h,c).
// ---------------------------------------------------------------------------
__global__ __launch_bounds__(256) void chunk_kv(
    const float* __restrict__ k, const float* __restrict__ v,
    float* __restrict__ kvchunk, float* __restrict__ kschunk,
    float* __restrict__ vschunk) {
  __shared__ float Ks[L_CHK][D_DIM];
  __shared__ float Vs[L_CHK][D_DIM];
  int blk = blockIdx.x;  // h*NC + c
  const size_t off = ((size_t)(blk / NC) * T_LEN + (blk % NC) * L_CHK) * D_DIM;
  int tid = threadIdx.x;
#pragma unroll
  for (int m = 0; m < 4; ++m) {
    int el = (tid + m * 256) * 4;
    *(float4*)&((float*)Ks)[el] = *(const float4*)&k[off + el];
    *(float4*)&((float*)Vs)[el] = *(const float4*)&v[off + el];
  }
  __syncthreads();
  int e = tid & 63;
  int q2 = tid >> 6;  // 0..3
  float acc[16] = {};
  for (int t = 0; t < L_CHK; ++t) {
    float ve = Vs[t][e];
#pragma unroll
    for (int m = 0; m < 16; ++m) acc[m] += Ks[t][q2 * 16 + m] * ve;
  }
  float* outb = kvchunk + (size_t)blk * (D_DIM * D_DIM);
#pragma unroll
  for (int m = 0; m < 16; ++m) outb[(q2 * 16 + m) * D_DIM + e] = acc[m];
  if (tid < 64) {
    float s = 0.f;
    for (int t = 0; t < L_CHK; ++t) s += Ks[t][tid];
    kschunk[(size_t)blk * D_DIM + tid] = s;
  } else if (tid < 128) {
    float s = 0.f;
    for (int t = 0; t < L_CHK; ++t) s += Vs[t][tid - 64];
    vschunk[(size_t)blk * D_DIM + (tid - 64)] = s;
  }
}

// ---------------------------------------------------------------------------
// Fused exclusive prefix scans over chunks: blocks 0..255 do the D*D state,
// blocks 256..259 do the ksum/vsum vectors. Fully unrolled loads.
// ---------------------------------------------------------------------------
__global__ __launch_bounds__(256) void scan_fused(
    const float* __restrict__ kvchunk, float* __restrict__ kvpref,
    const float* __restrict__ kschunk, const float* __restrict__ vschunk,
    float* __restrict__ kspref, float* __restrict__ vspref) {
  int b = blockIdx.x;
  int tid = threadIdx.x;
  if (b < 256) {
    int gid = b * 256 + tid;  // h*4096 + de
    int h = gid >> 12;
    int de = gid & 4095;
    float vals[NC];
#pragma unroll
    for (int c = 0; c < NC; ++c)
      vals[c] = kvchunk[((size_t)(h * NC + c) << 12) + de];
    float run = 0.f;
#pragma unroll
    for (int c = 0; c < NC; ++c) {
      kvpref[((size_t)(h * NC + c) << 12) + de] = run;
      run += vals[c];
    }
  } else {
    int gid = (b - 256) * 256 + tid;  // h*64 + d (total 1024)
    int h = gid >> 6, d = gid & 63;
    float kv_[NC], vv_[NC];
#pragma unroll
    for (int c = 0; c < NC; ++c) {
      size_t idx = (size_t)(h * NC + c) * 64 + d;
      kv_[c] = kschunk[idx];
      vv_[c] = vschunk[idx];
    }
    float rk = 0.f, rv = 0.f;
#pragma unroll
    for (int c = 0; c < NC; ++c) {
      size_t idx = (size_t)(h * NC + c) * 64 + d;
      kspref[idx] = rk;
      vspref[idx] = rv;
      rk += kv_[c];
      rv += vv_[c];
    }
  }
}

// ---------------------------------------------------------------------------
// Per-(head,chunk) output -> yh fp16, (T, H*D) layout.
// 256 threads: r = tid&63 (row), g = tid>>6 (16-dim quarter).
// ---------------------------------------------------------------------------
__global__ __launch_bounds__(256) void attn_out(
    const float* __restrict__ q, const float* __restrict__ k,
    const float* __restrict__ v, const float* __restrict__ kvpref,
    const float* __restrict__ kspref, const float* __restrict__ vspref,
    _Float16* __restrict__ yh) {
  __shared__ float Ks[L_CHK * D_DIM];       // phase1: K rows; phase2: KVpref
  __shared__ float Vs[L_CHK * D_DIM];
  __shared__ float Ss[L_CHK][L_CHK + 1];    // stride 65: column access free
  int blk = blockIdx.x;  // h*NC + c
  int h = blk / NC, c = blk % NC;
  int tid = threadIdx.x;
  int r = tid & 63;
  int g = tid >> 6;  // 0..3
  const size_t off = ((size_t)h * T_LEN + c * L_CHK) * D_DIM;
#pragma unroll
  for (int m = 0; m < 4; ++m) {
    int el = (tid + m * 256) * 4;
    *(float4*)&Ks[el] = *(const float4*)&k[off + el];
    *(float4*)&Vs[el] = *(const float4*)&v[off + el];
  }
  float qv[D_DIM];
#pragma unroll
  for (int i = 0; i < 16; ++i) {
    float4 t4 = *(const float4*)&q[off + r * D_DIM + i * 4];
    qv[i * 4 + 0] = t4.x; qv[i * 4 + 1] = t4.y;
    qv[i * 4 + 2] = t4.z; qv[i * 4 + 3] = t4.w;
  }
  __syncthreads();
#pragma unroll
  for (int jj = 0; jj < 16; ++jj) {
    int j = g * 16 + jj;
    const float4* krow = (const float4*)&Ks[j * D_DIM];  // wave-broadcast
    float sdot = 0.f;
#pragma unroll
    for (int i = 0; i < 16; ++i) {
      float4 kj = krow[i];
      sdot += qv[i * 4] * kj.x + qv[i * 4 + 1] * kj.y + qv[i * 4 + 2] * kj.z +
              qv[i * 4 + 3] * kj.w;
    }
    Ss[r][j] = (j <= r) ? (sdot + 1.f) : 0.f;
  }
  __syncthreads();
  const float* kvp = kvpref + (size_t)blk * (D_DIM * D_DIM);
#pragma unroll
  for (int m = 0; m < 4; ++m) {
    int el = (tid + m * 256) * 4;
    *(float4*)&Ks[el] = *(const float4*)&kvp[el];
  }
  __syncthreads();
  const float* ksp = kspref + (size_t)blk * D_DIM;
  const float* vsp = vspref + (size_t)blk * D_DIM;
  float den = (float)(c * L_CHK);  // rowsum(S) supplies the (r+1)
#pragma unroll
  for (int i = 0; i < 16; ++i) {
    float4 kk = *(const float4*)&ksp[i * 4];
    den += qv[i * 4] * kk.x + qv[i * 4 + 1] * kk.y + qv[i * 4 + 2] * kk.z +
           qv[i * 4 + 3] * kk.w;
  }
  float4 num[4];
#pragma unroll
  for (int i = 0; i < 4; ++i) num[i] = *(const float4*)&vsp[g * 16 + i * 4];
#pragma unroll
  for (int d = 0; d < D_DIM; ++d) {
    float qd = qv[d];
    const float4* kvrow = (const float4*)&Ks[d * D_DIM + g * 16];
#pragma unroll
    for (int i = 0; i < 4; ++i) {
      float4 k4 = kvrow[i];
      num[i].x += qd * k4.x; num[i].y += qd * k4.y;
      num[i].z += qd * k4.z; num[i].w += qd * k4.w;
    }
  }
  float rs = 0.f;
#pragma unroll 8
  for (int j = 0; j < L_CHK; ++j) {
    float f = Ss[r][j];
    rs += f;
    const float4* vrow = (const float4*)&Vs[j * D_DIM + g * 16];
#pragma unroll
    for (int i = 0; i < 4; ++i) {
      float4 v4 = vrow[i];
      num[i].x += f * v4.x; num[i].y += f * v4.y;
      num[i].z += f * v4.z; num[i].w += f * v4.w;
    }
  }
  den += rs;
  float inv = 1.f / den;
  int t = c * L_CHK + r;
  size_t ybase = (size_t)t * (H_NUM * D_DIM) + h * D_DIM + g * 16;
#pragma unroll
  for (int i = 0; i < 4; ++i) {
    h4 hv;
    hv[0] = (_Float16)(num[i].x * inv);
    hv[1] = (_Float16)(num[i].y * inv);
    hv[2] = (_Float16)(num[i].z * inv);
    hv[3] = (_Float16)(num[i].w * inv);
    *(h4*)&yh[ybase + i * 4] = hv;
  }
}

// ---------------------------------------------------------------------------
extern "C" void kernel_launch(void* const* d_in, const int* in_sizes, int n_in,
                              void* d_out, int out_size, void* d_ws,
                              size_t ws_size, hipStream_t stream) {
  const float* x = (const float*)d_in[0];       // (1,2048,1024)
  const float* w_attn = (const float*)d_in[1];  // (3072,1024)
  const float* w_proj = (const float*)d_in[2];  // (1024,1024)
  const float* cosb = (const float*)d_in[3];    // (2048,64)
  const float* sinb = (const float*)d_in[4];    // (2048,64)
  float* out = (float*)d_out;                   // (2048,1024)

  char* ws = (char*)d_ws;
  // Region A (0..16MB): kvchunk, kvpref
  float* kvchunk = (float*)ws;                       // 8 MB
  float* kvpref = (float*)(ws + 8388608);            // 8 MB
  // Region B (24..48MB): q/k/v fp32
  float* qbuf = (float*)(ws + 25165824);
  float* kbuf = (float*)(ws + 25165824 + 8388608);
  float* vbuf = (float*)(ws + 25165824 + 16777216);
  // Region C (48..56MB): xh/xl (live split->QKV GEMM); then yh.
  _Float16* xh = (_Float16*)(ws + 50331648);
  _Float16* xl = (_Float16*)(ws + 50331648 + 4194304);
  _Float16* yh = (_Float16*)(ws + 50331648);
  // Region D (56..68MB): wah/wal (live split->QKV GEMM); then scan vectors.
  _Float16* wah = (_Float16*)(ws + 58720256);
  _Float16* wal = (_Float16*)(ws + 58720256 + 6291456);
  float* kschunk = (float*)(ws + 58720256);
  float* vschunk = (float*)(ws + 58720256 + 131072);
  float* kspref = (float*)(ws + 58720256 + 262144);
  float* vspref = (float*)(ws + 58720256 + 393216);
  // Region E (68..72MB): wph (live whole call).
  _Float16* wph = (_Float16*)(ws + 71303168);

  // 0) fused splits (scale 64, undone in epilogues); w_proj hi-only
  split3_f16<<<3072, 256, 0, stream>>>(x, xh, xl, w_attn, wah, wal, w_proj,
                                       wph);

  // 1) qkv GEMM (f16x3, BK=64, swizzled) + fused RoPE -> q,k,v; 2^-12
  {
    dim3 grid(QKV_N / 128, T_LEN / 64);   // 24 x 32 = 768 blocks
    gemm_nt_f16<128, true, true><<<grid, 256, 0, stream>>>(
        xh, xl, wah, wal, nullptr, cosb, sinb, qbuf, kbuf, vbuf, T_LEN, QKV_N,
        C_DIM, 1.f / 4096.f);
  }
  // 2) per-chunk sums
  chunk_kv<<<H_NUM * NC, 256, 0, stream>>>(kbuf, vbuf, kvchunk, kschunk,
                                           vschunk);
  // 3) fused prefix scans (256 blocks kv + 4 blocks vec)
  scan_fused<<<260, 256, 0, stream>>>(kvchunk, kvpref, kschunk, vschunk,
                                      kspref, vspref);
  // 4) attention output -> yh (T, H*D) fp16
  attn_out<<<H_NUM * NC, 256, 0, stream>>>(qbuf, kbuf, vbuf, kvpref, kspref,
                                           vspref, yh);
  // 5) out = y @ w_proj^T (plain fp16, BK=64, swizzled): 2^-6
  {
    dim3 grid(C_DIM / 64, T_LEN / 64);    // 16 x 32 = 512 blocks
    gemm_nt_f16<64, false, false><<<grid, 256, 0, stream>>>(
        yh, nullptr, wph, nullptr, out, nullptr, nullptr, nullptr, nullptr,
        nullptr, T_LEN, C_DIM, C_DIM, 1.f / 64.f);
  }
}